// Round 10
// baseline (602.497 us; speedup 1.0000x reference)
//
#include <hip/hip_runtime.h>
#include <hip/hip_fp16.h>
#include <cfloat>

#define BB 4
#define NN 4096
#define KK 16
#define NPTS (BB * NN)      // 16384
#define NT48 (48 * NPTS)    // per-layer tay f16 elements, layout [48][NPTS]

typedef __attribute__((ext_vector_type(8))) _Float16 f16x8;
typedef __attribute__((ext_vector_type(4))) float f32x4;
typedef unsigned int u32;
typedef unsigned long long u64;

__device__ __forceinline__ short f2h(float v) {
  __half h = __float2half_rn(v);
  return __half_as_short(h);
}
__device__ __forceinline__ u32 mulh2(u32 a, __half2 t) {
  __half2 x = __hmul2(*(__half2*)&a, t);
  return *(u32*)&x;
}

// ---------------- pc -> ft0 f16 [p][8] + xyzq f32 [p][4] ----------------
__global__ __launch_bounds__(256) void pc2ft_kernel(const float* __restrict__ pc,
                                                    short* __restrict__ ft0,
                                                    float4* __restrict__ xyzq) {
  const int i = blockIdx.x * 256 + threadIdx.x;
  if (i >= NPTS) return;
  const float* s = pc + (size_t)i * 6;
  short* d = ft0 + (size_t)i * 8;
#pragma unroll
  for (int c = 0; c < 6; ++c) d[c] = f2h(s[c]);
  d[6] = 0; d[7] = 0;
  const float x = s[0], y = s[1], z = s[2];
  xyzq[i] = make_float4(x, y, z, fmaf(z, z, fmaf(y, y, x * x)));
}

// ---------------- KNN: min-threshold select, one block per query ----------------
__global__ __launch_bounds__(256) void knn_select(const float4* __restrict__ xyzq,
                                                  int* __restrict__ idx_out) {
  __shared__ float wT[4];
  __shared__ u64 list[128];
  __shared__ int lcnt;
  const int g = blockIdx.x;   // query point (b*4096 + n)
  const int b = g >> 12;
  const int t = threadIdx.x;
  const int lane = t & 63;
  const float4* base = xyzq + (b << 12);
  const float4 q = xyzq[g];
  float d2v[16];
  float mymin = FLT_MAX;
#pragma unroll
  for (int i = 0; i < 16; ++i) {
    const float4 c = base[i * 256 + t];
    const float dot = fmaf(q.z, c.z, fmaf(q.y, c.y, q.x * c.x));
    d2v[i] = fmaf(-2.0f, dot, q.w + c.w);
    mymin = fminf(mymin, d2v[i]);
  }
  if (t == 0) lcnt = 0;
  // ---- in-wave bitonic sort (ascending) of 64 thread-mins ----
  float v = mymin;
#pragma unroll
  for (int k = 2; k <= 64; k <<= 1) {
#pragma unroll
    for (int j = k >> 1; j >= 1; j >>= 1) {
      const float o = __shfl_xor(v, j, 64);
      const bool take_min = (((lane & k) == 0) == ((lane & j) == 0));
      v = take_min ? fminf(v, o) : fmaxf(v, o);
    }
  }
  const float tw = __shfl(v, 15, 64);  // 16th smallest in this wave
  if (lane == 0) wT[t >> 6] = tw;
  __syncthreads();  // covers wT + lcnt
  const float T = fminf(fminf(wT[0], wT[1]), fminf(wT[2], wT[3]));
  // ---- collect all candidates with d2 <= T (superset of top-16) ----
#pragma unroll
  for (int i = 0; i < 16; ++i) {
    if (d2v[i] <= T) {
      const u32 bits = __float_as_uint(d2v[i]);
      const u32 key = bits ^ ((u32)((int)bits >> 31) | 0x80000000u);
      const int pos = atomicAdd(&lcnt, 1);
      if (pos < 128) list[pos] = ((u64)key << 32) | (u32)(i * 256 + t);
    }
  }
  __syncthreads();
  // ---- rank-based extraction: lanes 0..127 own one entry each ----
  if (t < 128) {
    const int m = min(lcnt, 128);
    const u64 my = (t < m) ? list[t] : ~0ull;
    int rank = 0;
#pragma unroll 4
    for (int i = 0; i < m; ++i) rank += (list[i] < my) ? 1 : 0;
    if (t < m && rank < 16)
      idx_out[(size_t)g * KK + rank] = (int)(my & 0xFFFFFFFFull);
  }
}

// ---------------- weights fp32 (o,(c,t),k) -> f16 permuted [o][(t,k,c)] padded ----------------
__global__ __launch_bounds__(256) void wcvt_kernel(const float* __restrict__ w2,
                                                   short* __restrict__ wb,
                                                   int CIN, int COUT, int CPAD, int LOGC,
                                                   int total8) {
  const int i = blockIdx.x * 256 + threadIdx.x;
  if (i >= total8) return;
  const int q8 = i * 8;
  const int QT = CPAD * 48;
  const int o = q8 / QT;
  const int r = q8 - o * QT;
  const int kq = r >> LOGC;
  const int c0 = r & (CPAD - 1);
  const int tt = kq >> 4;
  const int k = kq & 15;
  short h[8];
#pragma unroll
  for (int j = 0; j < 8; ++j) {
    const int c = c0 + j;
    const float v = (o < COUT && c < CIN) ? w2[(size_t)o * CIN * 48 + (c * 3 + tt) * 16 + k] : 0.0f;
    h[j] = f2h(v);
  }
  short* d = wb + (size_t)o * QT + r;
#pragma unroll
  for (int j = 0; j < 8; ++j) d[j] = h[j];
}

// ---------------- tay_h[l][t*16+k][p] = f16(w1_l @ taylor(rel) + b1_l) ----------------
__global__ __launch_bounds__(256) void taylor_kernel(
    const float* __restrict__ pc, const int* __restrict__ idx,
    const float* __restrict__ w1_1, const float* __restrict__ b1_1,
    const float* __restrict__ w1_2, const float* __restrict__ b1_2,
    const float* __restrict__ w1_3, const float* __restrict__ b1_3,
    const float* __restrict__ w1_4, const float* __restrict__ b1_4,
    short* __restrict__ tayh) {
  const int i = blockIdx.x * 256 + threadIdx.x;  // p fastest, then k
  if (i >= NPTS * KK) return;
  const int p = i & (NPTS - 1);
  const int k = i >> 14;
  const int n = p & (NN - 1);
  const int b = p >> 12;
  const float* pcb = pc + (size_t)b * NN * 6;
  const int m = idx[(size_t)p * KK + k];
  const float x = pcb[m * 6 + 0] - pcb[n * 6 + 0];
  const float y = pcb[m * 6 + 1] - pcb[n * 6 + 1];
  const float z = pcb[m * 6 + 2] - pcb[n * 6 + 2];
  float tb[20];
  tb[0] = 1.0f; tb[1] = x; tb[2] = y; tb[3] = z;
  tb[4] = x * x; tb[5] = x * y; tb[6] = x * z;
  tb[7] = y * y; tb[8] = y * z; tb[9] = z * z;
  tb[10] = tb[4] * x; tb[11] = tb[4] * y; tb[12] = tb[4] * z;
  tb[13] = tb[5] * y; tb[14] = tb[5] * z; tb[15] = tb[6] * z;
  tb[16] = tb[7] * y; tb[17] = tb[7] * z; tb[18] = tb[8] * z; tb[19] = tb[9] * z;
  const float* w1s[4] = {w1_1, w1_2, w1_3, w1_4};
  const float* b1s[4] = {b1_1, b1_2, b1_3, b1_4};
#pragma unroll
  for (int l = 0; l < 4; ++l) {
    const float* w1 = w1s[l];
    const float* b1 = b1s[l];
#pragma unroll
    for (int c = 0; c < 3; ++c) {
      float s = b1[c];
#pragma unroll
      for (int j = 0; j < 20; ++j) s = fmaf(w1[c * 20 + j], tb[j], s);
      tayh[(size_t)(l * 48 + c * 16 + k) * NPTS + p] = f2h(s);
    }
  }
}

// ---------------- spider conv via f16 MFMA; A in LDS (swizzled DMA, dbuf), B in registers ----------------
// B frag is lane-local: built by its consumer from one 16B feat gather x scalar
// f16 tay (prefetched one outer ahead). LDS holds only A + read-only tay/idx.
// One __syncthreads per outer (K=64, 16 MFMA for NJ=2).
template <int CPAD, int LOGC, int COUT, int OTILE>
__global__ __launch_bounds__(256) void conv_mfma_kernel(
    const char* __restrict__ ftin,        // f16 [NPTS][CPAD]
    const short* __restrict__ wb,         // f16 [OPAD][QTOT] permuted
    const float* __restrict__ b2,
    const short* __restrict__ tayl,       // f16 [48][NPTS] (this layer)
    const int* __restrict__ idx,
    float* __restrict__ pfout, int pfbstride,
    short* __restrict__ ftout, int CPADN) {
  constexpr int QTOT = CPAD * 48;
  constexpr int OUTER = QTOT / 64;
  constexpr int NJ = OTILE / 64;   // 2 (OTILE=128) or 1 (OTILE=64)
  constexpr int PW = 16 * NJ;
  constexpr int NH = OTILE / 32;   // dma calls per A buffer
  __shared__ __align__(16) short As[2][OTILE * 64];
  __shared__ __align__(16) unsigned short tayH[48 * 64];
  __shared__ int idxS[16 * 64];
  const int t = threadIdx.x;
  const int pbase = blockIdx.x * 64;
  const int obase = blockIdx.y * OTILE;
  const int b = pbase >> 12;
  const int nbase = pbase & (NN - 1);
  const int p_loc = t >> 2;
  const int sub = t & 3;
  // ---- stage f16 tay tile [48][64] + neighbor byte-offsets ----
#pragma unroll
  for (int i = 0; i < 3; ++i) {
    const int f = i * 1024 + t * 4;
    *(ushort4*)&tayH[f] =
        *(const ushort4*)&tayl[(size_t)(f >> 6) * NPTS + pbase + (f & 63)];
  }
  {
    const int4 mi = *(const int4*)&idx[(size_t)(pbase + p_loc) * KK + sub * 4];
    const int gb = b << 12;
    idxS[(sub * 4 + 0) * 64 + p_loc] = (gb + mi.x) << (LOGC + 1);
    idxS[(sub * 4 + 1) * 64 + p_loc] = (gb + mi.y) << (LOGC + 1);
    idxS[(sub * 4 + 2) * 64 + p_loc] = (gb + mi.z) << (LOGC + 1);
    idxS[(sub * 4 + 3) * 64 + p_loc] = (gb + mi.w) << (LOGC + 1);
  }
  // ---- A dma lane setup (source permutation implements the XOR swizzle) ----
  const int arow = t >> 3;                 // 0..31
  const int apos = t & 7;                  // stored chunk position
  const int aswz = (t >> 4) & 7;           // (row>>1)&7
  const short* awl[NH];
#pragma unroll
  for (int h = 0; h < NH; ++h)
    awl[h] = wb + (size_t)(obase + h * 32 + arow) * QTOT + ((apos ^ aswz) * 8);
  auto dmaA = [&](int o, int ph) {
#pragma unroll
    for (int h = 0; h < NH; ++h)
      __builtin_amdgcn_global_load_lds(
          (const __attribute__((address_space(1))) u32*)(awl[h] + o * 64),
          (__attribute__((address_space(3))) u32*)&As[ph][h * 2048 + t * 8], 16, 0, 0);
  };
  // ---- wave mapping ----
  const int lane = t & 63;
  const int w = t >> 6;
  const int wm = (NJ == 2) ? (w & 1) : 0;
  const int wn = (NJ == 2) ? (w >> 1) : w;
  const int fr = lane & 15;
  const int fk = lane >> 4;
  const int rsw = (fr >> 1) & 7;           // frag-read un-swizzle
  f32x4 acc[4][NJ];
#pragma unroll
  for (int i = 0; i < 4; ++i)
#pragma unroll
    for (int j = 0; j < NJ; ++j) acc[i][j] = (f32x4)(0.0f);

  // ---- B prefetch state: lane-local fragments, double-buffered ----
  uint4 bfv[2][2][NJ];
  unsigned short tvh[2][2][NJ];
  auto prefB = [&](int o, int slot) {
#pragma unroll
    for (int z = 0; z < 2; ++z)
#pragma unroll
      for (int j = 0; j < NJ; ++j) {
        const int q0 = o * 64 + z * 32 + fk * 8;
        const int kq = q0 >> LOGC;
        const int c0 = q0 & (CPAD - 1);
        const int p_l = wn * PW + j * 16 + fr;
        const int moff = idxS[(kq & 15) * 64 + p_l];
        tvh[slot][z][j] = tayH[kq * 64 + p_l];
        bfv[slot][z][j] = *(const uint4*)(ftin + moff + (c0 << 1));
      }
  };
  // ---- prologue ----
  dmaA(0, 0);
  __syncthreads();            // tayH/idxS visible; dma0 drained
  prefB(0, 0);
#pragma unroll 1
  for (int o = 0; o < OUTER; ++o) {
    const int ph = o & 1;
    if (o + 1 < OUTER) { dmaA(o + 1, ph ^ 1); prefB(o + 1, ph ^ 1); }
#pragma unroll
    for (int z = 0; z < 2; ++z) {
      f16x8 af[4];
      const int pos8 = ((z * 4 + fk) ^ rsw) * 8;
#pragma unroll
      for (int i = 0; i < 4; ++i)
        af[i] = *(const f16x8*)&As[ph][(wm * 64 + i * 16 + fr) * 64 + pos8];
#pragma unroll
      for (int j = 0; j < NJ; ++j) {
        const __half2 t2 = __half2half2(__ushort_as_half(tvh[ph][z][j]));
        const uint4 fq = bfv[ph][z][j];
        uint4 r;
        r.x = mulh2(fq.x, t2); r.y = mulh2(fq.y, t2);
        r.z = mulh2(fq.z, t2); r.w = mulh2(fq.w, t2);
        const f16x8 bf = *(const f16x8*)&r;
#pragma unroll
        for (int i = 0; i < 4; ++i)
          acc[i][j] = __builtin_amdgcn_mfma_f32_16x16x32_f16(af[i], bf, acc[i][j], 0, 0, 0);
      }
    }
    if (o + 1 < OUTER) __syncthreads();  // As[ph] reads done; dma(o+1) drained
  }
  // ---- epilogue: bias + relu; fp32 -> pf, f16 -> ft_next ----
  float* outb = pfout + (size_t)b * pfbstride;
#pragma unroll
  for (int i = 0; i < 4; ++i) {
    const int o0 = obase + wm * 64 + i * 16 + fk * 4;
    if (o0 < COUT) {
      const float4 b4 = *(const float4*)&b2[o0];
#pragma unroll
      for (int j = 0; j < NJ; ++j) {
        const int p_l = wn * PW + j * 16 + fr;
        const float v0 = fmaxf(acc[i][j][0] + b4.x, 0.0f);
        const float v1 = fmaxf(acc[i][j][1] + b4.y, 0.0f);
        const float v2 = fmaxf(acc[i][j][2] + b4.z, 0.0f);
        const float v3 = fmaxf(acc[i][j][3] + b4.w, 0.0f);
        outb[(size_t)(o0 + 0) * NN + nbase + p_l] = v0;
        outb[(size_t)(o0 + 1) * NN + nbase + p_l] = v1;
        outb[(size_t)(o0 + 2) * NN + nbase + p_l] = v2;
        outb[(size_t)(o0 + 3) * NN + nbase + p_l] = v3;
        if (ftout) {
          const __half2 h01 = __floats2half2_rn(v0, v1);
          const __half2 h23 = __floats2half2_rn(v2, v3);
          uint2 pk;
          pk.x = *(const u32*)&h01;
          pk.y = *(const u32*)&h23;
          *(uint2*)&ftout[(size_t)(pbase + p_l) * CPADN + o0] = pk;
        }
      }
    }
  }
}

// ---------------- top-2 over N per (b, channel) ----------------
__global__ __launch_bounds__(256) void top2_kernel(const float* __restrict__ pf,
                                                   float* __restrict__ cat) {
  const int row = blockIdx.x;  // b*480 + ch
  const float* p = pf + (size_t)row * NN;
  float m1 = -FLT_MAX, m2 = -FLT_MAX;
  for (int i = threadIdx.x; i < NN; i += 256) {
    const float v = p[i];
    if (v > m1) { m2 = m1; m1 = v; }
    else if (v > m2) m2 = v;
  }
#pragma unroll
  for (int off = 32; off > 0; off >>= 1) {
    const float o1 = __shfl_down(m1, off, 64);
    const float o2 = __shfl_down(m2, off, 64);
    const float nm1 = fmaxf(m1, o1);
    const float nm2 = fmaxf(fminf(m1, o1), fmaxf(m2, o2));
    m1 = nm1; m2 = nm2;
  }
  __shared__ float s1[4], s2[4];
  const int wid = threadIdx.x >> 6;
  if ((threadIdx.x & 63) == 0) { s1[wid] = m1; s2[wid] = m2; }
  __syncthreads();
  if (threadIdx.x == 0) {
    m1 = s1[0]; m2 = s2[0];
#pragma unroll
    for (int w = 1; w < 4; ++w) {
      const float o1 = s1[w], o2 = s2[w];
      const float nm1 = fmaxf(m1, o1);
      const float nm2 = fmaxf(fminf(m1, o1), fmaxf(m2, o2));
      m1 = nm1; m2 = nm2;
    }
    const int b = row / 480, ch = row % 480;
    cat[b * 960 + ch * 2 + 0] = m1;
    cat[b * 960 + ch * 2 + 1] = m2;
  }
}

extern "C" void kernel_launch(void* const* d_in, const int* in_sizes, int n_in,
                              void* d_out, int out_size, void* d_ws, size_t ws_size,
                              hipStream_t stream) {
  const float* pc = (const float*)d_in[0];
  const float* w1s[4]; const float* b1s[4]; const float* w2s[4]; const float* b2s[4];
  for (int l = 0; l < 4; ++l) {
    w1s[l] = (const float*)d_in[1 + 4 * l];
    b1s[l] = (const float*)d_in[2 + 4 * l];
    w2s[l] = (const float*)d_in[3 + 4 * l];
    b2s[l] = (const float*)d_in[4 + 4 * l];
  }
  // ---- workspace layout (bytes) ----
  char* W = (char*)d_ws;
  int* idx = (int*)W;                                  // 1,048,576
  short* tayh = (short*)(W + 1048576);                 // 4 x 1,572,864 = 6,291,456 (f16)
  short* wb1 = (short*)(W + 13631488);                 // 64*384    f16 =    49,152 B
  short* wb2 = wb1 + 64 * 384;                         // 64*1536       =   196,608 B
  short* wb3 = wb2 + 64 * 1536;                        // 128*3072      =   786,432 B
  short* wb4 = wb3 + 128 * 3072;                       // 256*6144      = 3,145,728 B
  short* ft0 = (short*)(W + 17809408);                 // 16384*8  f16  =   262,144 B
  short* ft1 = (short*)(W + 18071552);                 // 16384*32      = 1,048,576 B
  // knn-phase alias (consumed before taylor writes):
  float4* xyzq = (float4*)(W + 1048576);               // 262,144 B, in tayh[0]
  // conv-phase aliases (placed after the 6.29 MB live tayh region):
  short* ft2 = (short*)(W + 1048576 + 6291456);        // 1 MB, written L2-epi
  short* ft3 = (short*)(W + 1048576 + 6291456 + 1048576);  // 2 MB, written L3-epi
  float* cat = (float*)d_out;                          // B*960
  float* pf = (float*)d_out + BB * 960;                // (B, 480, N)
  const int pfstride = 480 * NN;

  pc2ft_kernel<<<dim3(NPTS / 256), 256, 0, stream>>>(pc, ft0, xyzq);
  knn_select<<<dim3(NPTS), 256, 0, stream>>>(xyzq, idx);
  wcvt_kernel<<<dim3((64 * 384 / 8 + 255) / 256), 256, 0, stream>>>(w2s[0], wb1, 6, 32, 8, 3, 64 * 384 / 8);
  wcvt_kernel<<<dim3((64 * 1536 / 8 + 255) / 256), 256, 0, stream>>>(w2s[1], wb2, 32, 64, 32, 5, 64 * 1536 / 8);
  wcvt_kernel<<<dim3((128 * 3072 / 8 + 255) / 256), 256, 0, stream>>>(w2s[2], wb3, 64, 128, 64, 6, 128 * 3072 / 8);
  wcvt_kernel<<<dim3((256 * 6144 / 8 + 255) / 256), 256, 0, stream>>>(w2s[3], wb4, 128, 256, 128, 7, 256 * 6144 / 8);
  taylor_kernel<<<dim3(NPTS * KK / 256), 256, 0, stream>>>(
      pc, idx, w1s[0], b1s[0], w1s[1], b1s[1], w1s[2], b1s[2], w1s[3], b1s[3], tayh);
  conv_mfma_kernel<8, 3, 32, 64><<<dim3(NPTS / 64, 1), 256, 0, stream>>>(
      (const char*)ft0, wb1, b2s[0], tayh + 0 * (size_t)NT48, idx,
      pf + (size_t)0 * NN, pfstride, ft1, 32);
  conv_mfma_kernel<32, 5, 64, 64><<<dim3(NPTS / 64, 1), 256, 0, stream>>>(
      (const char*)ft1, wb2, b2s[1], tayh + 1 * (size_t)NT48, idx,
      pf + (size_t)32 * NN, pfstride, ft2, 64);
  conv_mfma_kernel<64, 6, 128, 64><<<dim3(NPTS / 64, 2), 256, 0, stream>>>(
      (const char*)ft2, wb3, b2s[2], tayh + 2 * (size_t)NT48, idx,
      pf + (size_t)96 * NN, pfstride, ft3, 128);
  conv_mfma_kernel<128, 7, 256, 128><<<dim3(NPTS / 64, 2), 256, 0, stream>>>(
      (const char*)ft3, wb4, b2s[3], tayh + 3 * (size_t)NT48, idx,
      pf + (size_t)224 * NN, pfstride, nullptr, 0);
  top2_kernel<<<dim3(BB * 480), 256, 0, stream>>>(pf, cat);
}

// Round 11
// 383.578 us; speedup vs baseline: 1.5707x; 1.5707x over previous
//
#include <hip/hip_runtime.h>
#include <hip/hip_fp16.h>
#include <cfloat>

#define BB 4
#define NN 4096
#define KK 16
#define NPTS (BB * NN)      // 16384
#define NT48 (48 * NPTS)    // per-layer tay f16 elements, layout [48][NPTS]

typedef __attribute__((ext_vector_type(8))) _Float16 f16x8;
typedef __attribute__((ext_vector_type(4))) float f32x4;
typedef unsigned int u32;
typedef unsigned long long u64;

__device__ __forceinline__ short f2h(float v) {
  __half h = __float2half_rn(v);
  return __half_as_short(h);
}
__device__ __forceinline__ u32 mulh2(u32 a, __half2 t) {
  __half2 x = __hmul2(*(__half2*)&a, t);
  return *(u32*)&x;
}

// ---------------- pc -> ft0 f16 [p][8] + xyzq f32 [p][4] ----------------
__global__ __launch_bounds__(256) void pc2ft_kernel(const float* __restrict__ pc,
                                                    short* __restrict__ ft0,
                                                    float4* __restrict__ xyzq) {
  const int i = blockIdx.x * 256 + threadIdx.x;
  if (i >= NPTS) return;
  const float* s = pc + (size_t)i * 6;
  short* d = ft0 + (size_t)i * 8;
#pragma unroll
  for (int c = 0; c < 6; ++c) d[c] = f2h(s[c]);
  d[6] = 0; d[7] = 0;
  const float x = s[0], y = s[1], z = s[2];
  xyzq[i] = make_float4(x, y, z, fmaf(z, z, fmaf(y, y, x * x)));
}

// ---------------- KNN: min-threshold select, one block per query ----------------
__global__ __launch_bounds__(256) void knn_select(const float4* __restrict__ xyzq,
                                                  int* __restrict__ idx_out) {
  __shared__ float wT[4];
  __shared__ u64 list[128];
  __shared__ int lcnt;
  const int g = blockIdx.x;   // query point (b*4096 + n)
  const int b = g >> 12;
  const int t = threadIdx.x;
  const int lane = t & 63;
  const float4* base = xyzq + (b << 12);
  const float4 q = xyzq[g];
  float d2v[16];
  float mymin = FLT_MAX;
#pragma unroll
  for (int i = 0; i < 16; ++i) {
    const float4 c = base[i * 256 + t];
    const float dot = fmaf(q.z, c.z, fmaf(q.y, c.y, q.x * c.x));
    d2v[i] = fmaf(-2.0f, dot, q.w + c.w);
    mymin = fminf(mymin, d2v[i]);
  }
  if (t == 0) lcnt = 0;
  // ---- in-wave bitonic sort (ascending) of 64 thread-mins ----
  float v = mymin;
#pragma unroll
  for (int k = 2; k <= 64; k <<= 1) {
#pragma unroll
    for (int j = k >> 1; j >= 1; j >>= 1) {
      const float o = __shfl_xor(v, j, 64);
      const bool take_min = (((lane & k) == 0) == ((lane & j) == 0));
      v = take_min ? fminf(v, o) : fmaxf(v, o);
    }
  }
  const float tw = __shfl(v, 15, 64);  // 16th smallest in this wave
  if (lane == 0) wT[t >> 6] = tw;
  __syncthreads();  // covers wT + lcnt
  const float T = fminf(fminf(wT[0], wT[1]), fminf(wT[2], wT[3]));
  // ---- collect all candidates with d2 <= T (superset of top-16) ----
#pragma unroll
  for (int i = 0; i < 16; ++i) {
    if (d2v[i] <= T) {
      const u32 bits = __float_as_uint(d2v[i]);
      const u32 key = bits ^ ((u32)((int)bits >> 31) | 0x80000000u);
      const int pos = atomicAdd(&lcnt, 1);
      if (pos < 128) list[pos] = ((u64)key << 32) | (u32)(i * 256 + t);
    }
  }
  __syncthreads();
  // ---- rank-based extraction: lanes 0..127 own one entry each ----
  if (t < 128) {
    const int m = min(lcnt, 128);
    const u64 my = (t < m) ? list[t] : ~0ull;
    int rank = 0;
#pragma unroll 4
    for (int i = 0; i < m; ++i) rank += (list[i] < my) ? 1 : 0;
    if (t < m && rank < 16)
      idx_out[(size_t)g * KK + rank] = (int)(my & 0xFFFFFFFFull);
  }
}

// ---------------- weights fp32 (o,(c,t),k) -> f16 permuted [o][(t,k,c)] padded ----------------
__global__ __launch_bounds__(256) void wcvt_kernel(const float* __restrict__ w2,
                                                   short* __restrict__ wb,
                                                   int CIN, int COUT, int CPAD, int LOGC,
                                                   int total8) {
  const int i = blockIdx.x * 256 + threadIdx.x;
  if (i >= total8) return;
  const int q8 = i * 8;
  const int QT = CPAD * 48;
  const int o = q8 / QT;
  const int r = q8 - o * QT;
  const int kq = r >> LOGC;
  const int c0 = r & (CPAD - 1);
  const int tt = kq >> 4;
  const int k = kq & 15;
  short h[8];
#pragma unroll
  for (int j = 0; j < 8; ++j) {
    const int c = c0 + j;
    const float v = (o < COUT && c < CIN) ? w2[(size_t)o * CIN * 48 + (c * 3 + tt) * 16 + k] : 0.0f;
    h[j] = f2h(v);
  }
  short* d = wb + (size_t)o * QT + r;
#pragma unroll
  for (int j = 0; j < 8; ++j) d[j] = h[j];
}

// ---------------- tay_h[l][t*16+k][p] = f16(w1_l @ taylor(rel) + b1_l) ----------------
__global__ __launch_bounds__(256) void taylor_kernel(
    const float* __restrict__ pc, const int* __restrict__ idx,
    const float* __restrict__ w1_1, const float* __restrict__ b1_1,
    const float* __restrict__ w1_2, const float* __restrict__ b1_2,
    const float* __restrict__ w1_3, const float* __restrict__ b1_3,
    const float* __restrict__ w1_4, const float* __restrict__ b1_4,
    short* __restrict__ tayh) {
  const int i = blockIdx.x * 256 + threadIdx.x;  // p fastest, then k
  if (i >= NPTS * KK) return;
  const int p = i & (NPTS - 1);
  const int k = i >> 14;
  const int n = p & (NN - 1);
  const int b = p >> 12;
  const float* pcb = pc + (size_t)b * NN * 6;
  const int m = idx[(size_t)p * KK + k];
  const float x = pcb[m * 6 + 0] - pcb[n * 6 + 0];
  const float y = pcb[m * 6 + 1] - pcb[n * 6 + 1];
  const float z = pcb[m * 6 + 2] - pcb[n * 6 + 2];
  float tb[20];
  tb[0] = 1.0f; tb[1] = x; tb[2] = y; tb[3] = z;
  tb[4] = x * x; tb[5] = x * y; tb[6] = x * z;
  tb[7] = y * y; tb[8] = y * z; tb[9] = z * z;
  tb[10] = tb[4] * x; tb[11] = tb[4] * y; tb[12] = tb[4] * z;
  tb[13] = tb[5] * y; tb[14] = tb[5] * z; tb[15] = tb[6] * z;
  tb[16] = tb[7] * y; tb[17] = tb[7] * z; tb[18] = tb[8] * z; tb[19] = tb[9] * z;
  const float* w1s[4] = {w1_1, w1_2, w1_3, w1_4};
  const float* b1s[4] = {b1_1, b1_2, b1_3, b1_4};
#pragma unroll
  for (int l = 0; l < 4; ++l) {
    const float* w1 = w1s[l];
    const float* b1 = b1s[l];
#pragma unroll
    for (int c = 0; c < 3; ++c) {
      float s = b1[c];
#pragma unroll
      for (int j = 0; j < 20; ++j) s = fmaf(w1[c * 20 + j], tb[j], s);
      tayh[(size_t)(l * 48 + c * 16 + k) * NPTS + p] = f2h(s);
    }
  }
}

// ---------------- spider conv via f16 MFMA; A in LDS (swizzled DMA, dbuf), B in registers ----------------
// B prefetch buffers are two NAMED register sets (bfv0/bfv1) -- all indices
// compile-time constant so they stay in VGPRs (R10's dynamic ph-index sent
// them to scratch: 700 MB HBM writes). Outer loop manually unrolled x2.
template <int CPAD, int LOGC, int COUT, int OTILE>
__global__ __launch_bounds__(256) void conv_mfma_kernel(
    const char* __restrict__ ftin,        // f16 [NPTS][CPAD]
    const short* __restrict__ wb,         // f16 [OPAD][QTOT] permuted
    const float* __restrict__ b2,
    const short* __restrict__ tayl,       // f16 [48][NPTS] (this layer)
    const int* __restrict__ idx,
    float* __restrict__ pfout, int pfbstride,
    short* __restrict__ ftout, int CPADN) {
  constexpr int QTOT = CPAD * 48;
  constexpr int OUTER = QTOT / 64;        // even for all layers: 6/24/48/96
  constexpr int NJ = OTILE / 64;          // 2 (OTILE=128) or 1 (OTILE=64)
  constexpr int PW = 16 * NJ;
  constexpr int NH = OTILE / 32;          // dma calls per A buffer
  __shared__ __align__(16) short As[2][OTILE * 64];
  __shared__ __align__(16) unsigned short tayH[48 * 64];
  __shared__ int idxS[16 * 64];
  const int t = threadIdx.x;
  const int pbase = blockIdx.x * 64;
  const int obase = blockIdx.y * OTILE;
  const int b = pbase >> 12;
  const int nbase = pbase & (NN - 1);
  const int p_loc = t >> 2;
  const int sub = t & 3;
  // ---- stage f16 tay tile [48][64] + neighbor byte-offsets ----
#pragma unroll
  for (int i = 0; i < 3; ++i) {
    const int f = i * 1024 + t * 4;
    *(ushort4*)&tayH[f] =
        *(const ushort4*)&tayl[(size_t)(f >> 6) * NPTS + pbase + (f & 63)];
  }
  {
    const int4 mi = *(const int4*)&idx[(size_t)(pbase + p_loc) * KK + sub * 4];
    const int gb = b << 12;
    idxS[(sub * 4 + 0) * 64 + p_loc] = (gb + mi.x) << (LOGC + 1);
    idxS[(sub * 4 + 1) * 64 + p_loc] = (gb + mi.y) << (LOGC + 1);
    idxS[(sub * 4 + 2) * 64 + p_loc] = (gb + mi.z) << (LOGC + 1);
    idxS[(sub * 4 + 3) * 64 + p_loc] = (gb + mi.w) << (LOGC + 1);
  }
  // ---- A dma lane setup (source permutation implements the XOR swizzle) ----
  const int arow = t >> 3;                 // 0..31
  const int apos = t & 7;                  // stored chunk position
  const int aswz = (t >> 4) & 7;           // (row>>1)&7
  const short* awl[NH];
#pragma unroll
  for (int h = 0; h < NH; ++h)
    awl[h] = wb + (size_t)(obase + h * 32 + arow) * QTOT + ((apos ^ aswz) * 8);
  auto dmaA = [&](int o, int ph) {
#pragma unroll
    for (int h = 0; h < NH; ++h)
      __builtin_amdgcn_global_load_lds(
          (const __attribute__((address_space(1))) u32*)(awl[h] + o * 64),
          (__attribute__((address_space(3))) u32*)&As[ph][h * 2048 + t * 8], 16, 0, 0);
  };
  // ---- wave mapping ----
  const int lane = t & 63;
  const int w = t >> 6;
  const int wm = (NJ == 2) ? (w & 1) : 0;
  const int wn = (NJ == 2) ? (w >> 1) : w;
  const int fr = lane & 15;
  const int fk = lane >> 4;
  const int rsw = (fr >> 1) & 7;           // frag-read un-swizzle
  f32x4 acc[4][NJ];
#pragma unroll
  for (int i = 0; i < 4; ++i)
#pragma unroll
    for (int j = 0; j < NJ; ++j) acc[i][j] = (f32x4)(0.0f);

  // ---- two NAMED B register sets (constant indices only -> stay in VGPRs) ----
  uint4 bfv0[2][NJ], bfv1[2][NJ];
  unsigned short tvh0[2][NJ], tvh1[2][NJ];
  auto prefB = [&](int o, uint4 (&bf)[2][NJ], unsigned short (&tv)[2][NJ]) {
#pragma unroll
    for (int z = 0; z < 2; ++z)
#pragma unroll
      for (int j = 0; j < NJ; ++j) {
        const int q0 = o * 64 + z * 32 + fk * 8;
        const int kq = q0 >> LOGC;
        const int c0 = q0 & (CPAD - 1);
        const int p_l = wn * PW + j * 16 + fr;
        const int moff = idxS[(kq & 15) * 64 + p_l];
        tv[z][j] = tayH[kq * 64 + p_l];
        bf[z][j] = *(const uint4*)(ftin + moff + (c0 << 1));
      }
  };
  auto consume = [&](const short* Ab, uint4 (&bf)[2][NJ],
                     unsigned short (&tv)[2][NJ]) {
#pragma unroll
    for (int z = 0; z < 2; ++z) {
      f16x8 af[4];
      const int pos8 = ((z * 4 + fk) ^ rsw) * 8;
#pragma unroll
      for (int i = 0; i < 4; ++i)
        af[i] = *(const f16x8*)&Ab[(wm * 64 + i * 16 + fr) * 64 + pos8];
#pragma unroll
      for (int j = 0; j < NJ; ++j) {
        const __half2 t2 = __half2half2(__ushort_as_half(tv[z][j]));
        const uint4 fq = bf[z][j];
        uint4 r;
        r.x = mulh2(fq.x, t2); r.y = mulh2(fq.y, t2);
        r.z = mulh2(fq.z, t2); r.w = mulh2(fq.w, t2);
        const f16x8 bfr = *(const f16x8*)&r;
#pragma unroll
        for (int i = 0; i < 4; ++i)
          acc[i][j] = __builtin_amdgcn_mfma_f32_16x16x32_f16(af[i], bfr, acc[i][j], 0, 0, 0);
      }
    }
  };
  // ---- prologue ----
  dmaA(0, 0);
  __syncthreads();            // tayH/idxS visible; dma0 drained
  prefB(0, bfv0, tvh0);
#pragma unroll 1
  for (int o = 0; o < OUTER; o += 2) {
    dmaA(o + 1, 1);
    prefB(o + 1, bfv1, tvh1);
    consume(As[0], bfv0, tvh0);
    __syncthreads();          // As[0] reads done; dma(o+1) drained
    if (o + 2 < OUTER) { dmaA(o + 2, 0); prefB(o + 2, bfv0, tvh0); }
    consume(As[1], bfv1, tvh1);
    if (o + 2 < OUTER) __syncthreads();  // As[1] reads done; dma(o+2) drained
  }
  // ---- epilogue: bias + relu; fp32 -> pf, f16 -> ft_next ----
  float* outb = pfout + (size_t)b * pfbstride;
#pragma unroll
  for (int i = 0; i < 4; ++i) {
    const int o0 = obase + wm * 64 + i * 16 + fk * 4;
    if (o0 < COUT) {
      const float4 b4 = *(const float4*)&b2[o0];
#pragma unroll
      for (int j = 0; j < NJ; ++j) {
        const int p_l = wn * PW + j * 16 + fr;
        const float v0 = fmaxf(acc[i][j][0] + b4.x, 0.0f);
        const float v1 = fmaxf(acc[i][j][1] + b4.y, 0.0f);
        const float v2 = fmaxf(acc[i][j][2] + b4.z, 0.0f);
        const float v3 = fmaxf(acc[i][j][3] + b4.w, 0.0f);
        outb[(size_t)(o0 + 0) * NN + nbase + p_l] = v0;
        outb[(size_t)(o0 + 1) * NN + nbase + p_l] = v1;
        outb[(size_t)(o0 + 2) * NN + nbase + p_l] = v2;
        outb[(size_t)(o0 + 3) * NN + nbase + p_l] = v3;
        if (ftout) {
          const __half2 h01 = __floats2half2_rn(v0, v1);
          const __half2 h23 = __floats2half2_rn(v2, v3);
          uint2 pk;
          pk.x = *(const u32*)&h01;
          pk.y = *(const u32*)&h23;
          *(uint2*)&ftout[(size_t)(pbase + p_l) * CPADN + o0] = pk;
        }
      }
    }
  }
}

// ---------------- top-2 over N per (b, channel) ----------------
__global__ __launch_bounds__(256) void top2_kernel(const float* __restrict__ pf,
                                                   float* __restrict__ cat) {
  const int row = blockIdx.x;  // b*480 + ch
  const float* p = pf + (size_t)row * NN;
  float m1 = -FLT_MAX, m2 = -FLT_MAX;
  for (int i = threadIdx.x; i < NN; i += 256) {
    const float v = p[i];
    if (v > m1) { m2 = m1; m1 = v; }
    else if (v > m2) m2 = v;
  }
#pragma unroll
  for (int off = 32; off > 0; off >>= 1) {
    const float o1 = __shfl_down(m1, off, 64);
    const float o2 = __shfl_down(m2, off, 64);
    const float nm1 = fmaxf(m1, o1);
    const float nm2 = fmaxf(fminf(m1, o1), fmaxf(m2, o2));
    m1 = nm1; m2 = nm2;
  }
  __shared__ float s1[4], s2[4];
  const int wid = threadIdx.x >> 6;
  if ((threadIdx.x & 63) == 0) { s1[wid] = m1; s2[wid] = m2; }
  __syncthreads();
  if (threadIdx.x == 0) {
    m1 = s1[0]; m2 = s2[0];
#pragma unroll
    for (int w = 1; w < 4; ++w) {
      const float o1 = s1[w], o2 = s2[w];
      const float nm1 = fmaxf(m1, o1);
      const float nm2 = fmaxf(fminf(m1, o1), fmaxf(m2, o2));
      m1 = nm1; m2 = nm2;
    }
    const int b = row / 480, ch = row % 480;
    cat[b * 960 + ch * 2 + 0] = m1;
    cat[b * 960 + ch * 2 + 1] = m2;
  }
}

extern "C" void kernel_launch(void* const* d_in, const int* in_sizes, int n_in,
                              void* d_out, int out_size, void* d_ws, size_t ws_size,
                              hipStream_t stream) {
  const float* pc = (const float*)d_in[0];
  const float* w1s[4]; const float* b1s[4]; const float* w2s[4]; const float* b2s[4];
  for (int l = 0; l < 4; ++l) {
    w1s[l] = (const float*)d_in[1 + 4 * l];
    b1s[l] = (const float*)d_in[2 + 4 * l];
    w2s[l] = (const float*)d_in[3 + 4 * l];
    b2s[l] = (const float*)d_in[4 + 4 * l];
  }
  // ---- workspace layout (bytes) ----
  char* W = (char*)d_ws;
  int* idx = (int*)W;                                  // 1,048,576
  short* tayh = (short*)(W + 1048576);                 // 4 x 1,572,864 = 6,291,456 (f16)
  short* wb1 = (short*)(W + 13631488);                 // 64*384    f16 =    49,152 B
  short* wb2 = wb1 + 64 * 384;                         // 64*1536       =   196,608 B
  short* wb3 = wb2 + 64 * 1536;                        // 128*3072      =   786,432 B
  short* wb4 = wb3 + 128 * 3072;                       // 256*6144      = 3,145,728 B
  short* ft0 = (short*)(W + 17809408);                 // 16384*8  f16  =   262,144 B
  short* ft1 = (short*)(W + 18071552);                 // 16384*32      = 1,048,576 B
  // knn-phase alias (consumed before taylor writes):
  float4* xyzq = (float4*)(W + 1048576);               // 262,144 B, in tayh[0]
  // conv-phase aliases (placed after the 6.29 MB live tayh region):
  short* ft2 = (short*)(W + 1048576 + 6291456);        // 1 MB, written L2-epi
  short* ft3 = (short*)(W + 1048576 + 6291456 + 1048576);  // 2 MB, written L3-epi
  float* cat = (float*)d_out;                          // B*960
  float* pf = (float*)d_out + BB * 960;                // (B, 480, N)
  const int pfstride = 480 * NN;

  pc2ft_kernel<<<dim3(NPTS / 256), 256, 0, stream>>>(pc, ft0, xyzq);
  knn_select<<<dim3(NPTS), 256, 0, stream>>>(xyzq, idx);
  wcvt_kernel<<<dim3((64 * 384 / 8 + 255) / 256), 256, 0, stream>>>(w2s[0], wb1, 6, 32, 8, 3, 64 * 384 / 8);
  wcvt_kernel<<<dim3((64 * 1536 / 8 + 255) / 256), 256, 0, stream>>>(w2s[1], wb2, 32, 64, 32, 5, 64 * 1536 / 8);
  wcvt_kernel<<<dim3((128 * 3072 / 8 + 255) / 256), 256, 0, stream>>>(w2s[2], wb3, 64, 128, 64, 6, 128 * 3072 / 8);
  wcvt_kernel<<<dim3((256 * 6144 / 8 + 255) / 256), 256, 0, stream>>>(w2s[3], wb4, 128, 256, 128, 7, 256 * 6144 / 8);
  taylor_kernel<<<dim3(NPTS * KK / 256), 256, 0, stream>>>(
      pc, idx, w1s[0], b1s[0], w1s[1], b1s[1], w1s[2], b1s[2], w1s[3], b1s[3], tayh);
  conv_mfma_kernel<8, 3, 32, 64><<<dim3(NPTS / 64, 1), 256, 0, stream>>>(
      (const char*)ft0, wb1, b2s[0], tayh + 0 * (size_t)NT48, idx,
      pf + (size_t)0 * NN, pfstride, ft1, 32);
  conv_mfma_kernel<32, 5, 64, 64><<<dim3(NPTS / 64, 1), 256, 0, stream>>>(
      (const char*)ft1, wb2, b2s[1], tayh + 1 * (size_t)NT48, idx,
      pf + (size_t)32 * NN, pfstride, ft2, 64);
  conv_mfma_kernel<64, 6, 128, 64><<<dim3(NPTS / 64, 2), 256, 0, stream>>>(
      (const char*)ft2, wb3, b2s[2], tayh + 2 * (size_t)NT48, idx,
      pf + (size_t)96 * NN, pfstride, ft3, 128);
  conv_mfma_kernel<128, 7, 256, 128><<<dim3(NPTS / 64, 2), 256, 0, stream>>>(
      (const char*)ft3, wb4, b2s[3], tayh + 3 * (size_t)NT48, idx,
      pf + (size_t)224 * NN, pfstride, nullptr, 0);
  top2_kernel<<<dim3(BB * 480), 256, 0, stream>>>(pf, cat);
}

// Round 12
// 356.995 us; speedup vs baseline: 1.6877x; 1.0745x over previous
//
#include <hip/hip_runtime.h>
#include <hip/hip_fp16.h>
#include <cfloat>

#define BB 4
#define NN 4096
#define KK 16
#define NPTS (BB * NN)      // 16384
#define NT48 (48 * NPTS)    // per-layer tay f16 elements, layout [48][NPTS]

typedef __attribute__((ext_vector_type(8))) _Float16 f16x8;
typedef __attribute__((ext_vector_type(4))) float f32x4;
typedef unsigned int u32;
typedef unsigned long long u64;

__device__ __forceinline__ short f2h(float v) {
  __half h = __float2half_rn(v);
  return __half_as_short(h);
}
__device__ __forceinline__ u32 mulh2(u32 a, __half2 t) {
  __half2 x = __hmul2(*(__half2*)&a, t);
  return *(u32*)&x;
}

// ---------------- pc -> ft0 f16 [p][8] + xyzq f32 [p][4] ----------------
__global__ __launch_bounds__(256) void pc2ft_kernel(const float* __restrict__ pc,
                                                    short* __restrict__ ft0,
                                                    float4* __restrict__ xyzq) {
  const int i = blockIdx.x * 256 + threadIdx.x;
  if (i >= NPTS) return;
  const float* s = pc + (size_t)i * 6;
  short* d = ft0 + (size_t)i * 8;
#pragma unroll
  for (int c = 0; c < 6; ++c) d[c] = f2h(s[c]);
  d[6] = 0; d[7] = 0;
  const float x = s[0], y = s[1], z = s[2];
  xyzq[i] = make_float4(x, y, z, fmaf(z, z, fmaf(y, y, x * x)));
}

// ---------------- KNN: min-threshold select, one block per query ----------------
__global__ __launch_bounds__(256) void knn_select(const float4* __restrict__ xyzq,
                                                  int* __restrict__ idx_out) {
  __shared__ float wT[4];
  __shared__ u64 list[128];
  __shared__ int lcnt;
  const int g = blockIdx.x;   // query point (b*4096 + n)
  const int b = g >> 12;
  const int t = threadIdx.x;
  const int lane = t & 63;
  const float4* base = xyzq + (b << 12);
  const float4 q = xyzq[g];
  float d2v[16];
  float mymin = FLT_MAX;
#pragma unroll
  for (int i = 0; i < 16; ++i) {
    const float4 c = base[i * 256 + t];
    const float dot = fmaf(q.z, c.z, fmaf(q.y, c.y, q.x * c.x));
    d2v[i] = fmaf(-2.0f, dot, q.w + c.w);
    mymin = fminf(mymin, d2v[i]);
  }
  if (t == 0) lcnt = 0;
  // ---- in-wave bitonic sort (ascending) of 64 thread-mins ----
  float v = mymin;
#pragma unroll
  for (int k = 2; k <= 64; k <<= 1) {
#pragma unroll
    for (int j = k >> 1; j >= 1; j >>= 1) {
      const float o = __shfl_xor(v, j, 64);
      const bool take_min = (((lane & k) == 0) == ((lane & j) == 0));
      v = take_min ? fminf(v, o) : fmaxf(v, o);
    }
  }
  const float tw = __shfl(v, 15, 64);  // 16th smallest in this wave
  if (lane == 0) wT[t >> 6] = tw;
  __syncthreads();  // covers wT + lcnt
  const float T = fminf(fminf(wT[0], wT[1]), fminf(wT[2], wT[3]));
  // ---- collect all candidates with d2 <= T (superset of top-16) ----
#pragma unroll
  for (int i = 0; i < 16; ++i) {
    if (d2v[i] <= T) {
      const u32 bits = __float_as_uint(d2v[i]);
      const u32 key = bits ^ ((u32)((int)bits >> 31) | 0x80000000u);
      const int pos = atomicAdd(&lcnt, 1);
      if (pos < 128) list[pos] = ((u64)key << 32) | (u32)(i * 256 + t);
    }
  }
  __syncthreads();
  // ---- rank-based extraction: lanes 0..127 own one entry each ----
  if (t < 128) {
    const int m = min(lcnt, 128);
    const u64 my = (t < m) ? list[t] : ~0ull;
    int rank = 0;
#pragma unroll 4
    for (int i = 0; i < m; ++i) rank += (list[i] < my) ? 1 : 0;
    if (t < m && rank < 16)
      idx_out[(size_t)g * KK + rank] = (int)(my & 0xFFFFFFFFull);
  }
}

// ---------------- weights fp32 (o,(c,t),k) -> f16 permuted [o][(t,k,c)] padded ----------------
__global__ __launch_bounds__(256) void wcvt_kernel(const float* __restrict__ w2,
                                                   short* __restrict__ wb,
                                                   int CIN, int COUT, int CPAD, int LOGC,
                                                   int total8) {
  const int i = blockIdx.x * 256 + threadIdx.x;
  if (i >= total8) return;
  const int q8 = i * 8;
  const int QT = CPAD * 48;
  const int o = q8 / QT;
  const int r = q8 - o * QT;
  const int kq = r >> LOGC;
  const int c0 = r & (CPAD - 1);
  const int tt = kq >> 4;
  const int k = kq & 15;
  short h[8];
#pragma unroll
  for (int j = 0; j < 8; ++j) {
    const int c = c0 + j;
    const float v = (o < COUT && c < CIN) ? w2[(size_t)o * CIN * 48 + (c * 3 + tt) * 16 + k] : 0.0f;
    h[j] = f2h(v);
  }
  short* d = wb + (size_t)o * QT + r;
#pragma unroll
  for (int j = 0; j < 8; ++j) d[j] = h[j];
}

// ---------------- tay_h[l][t*16+k][p] = f16(w1_l @ taylor(rel) + b1_l) ----------------
__global__ __launch_bounds__(256) void taylor_kernel(
    const float* __restrict__ pc, const int* __restrict__ idx,
    const float* __restrict__ w1_1, const float* __restrict__ b1_1,
    const float* __restrict__ w1_2, const float* __restrict__ b1_2,
    const float* __restrict__ w1_3, const float* __restrict__ b1_3,
    const float* __restrict__ w1_4, const float* __restrict__ b1_4,
    short* __restrict__ tayh) {
  const int i = blockIdx.x * 256 + threadIdx.x;  // p fastest, then k
  if (i >= NPTS * KK) return;
  const int p = i & (NPTS - 1);
  const int k = i >> 14;
  const int n = p & (NN - 1);
  const int b = p >> 12;
  const float* pcb = pc + (size_t)b * NN * 6;
  const int m = idx[(size_t)p * KK + k];
  const float x = pcb[m * 6 + 0] - pcb[n * 6 + 0];
  const float y = pcb[m * 6 + 1] - pcb[n * 6 + 1];
  const float z = pcb[m * 6 + 2] - pcb[n * 6 + 2];
  float tb[20];
  tb[0] = 1.0f; tb[1] = x; tb[2] = y; tb[3] = z;
  tb[4] = x * x; tb[5] = x * y; tb[6] = x * z;
  tb[7] = y * y; tb[8] = y * z; tb[9] = z * z;
  tb[10] = tb[4] * x; tb[11] = tb[4] * y; tb[12] = tb[4] * z;
  tb[13] = tb[5] * y; tb[14] = tb[5] * z; tb[15] = tb[6] * z;
  tb[16] = tb[7] * y; tb[17] = tb[7] * z; tb[18] = tb[8] * z; tb[19] = tb[9] * z;
  const float* w1s[4] = {w1_1, w1_2, w1_3, w1_4};
  const float* b1s[4] = {b1_1, b1_2, b1_3, b1_4};
#pragma unroll
  for (int l = 0; l < 4; ++l) {
    const float* w1 = w1s[l];
    const float* b1 = b1s[l];
#pragma unroll
    for (int c = 0; c < 3; ++c) {
      float s = b1[c];
#pragma unroll
      for (int j = 0; j < 20; ++j) s = fmaf(w1[c * 20 + j], tb[j], s);
      tayh[(size_t)(l * 48 + c * 16 + k) * NPTS + p] = f2h(s);
    }
  }
}

// ---------------- spider conv via f16 MFMA; A+B in LDS (R9 skeleton) ----------------
// OTILE=64 (L1-L3): R9 mapping, wave = 64o x 16p.
// OTILE=128 (L4): k-split mapping, wave = 64o x 64p x half-K; A-frag reads halved;
// ks-pairs merge partial sums via one end-of-kernel LDS reduction (reuses As).
template <int CPAD, int LOGC, int COUT, int OTILE>
__global__ __launch_bounds__(256) void conv_mfma_kernel(
    const char* __restrict__ ftin,        // f16 [NPTS][CPAD]
    const short* __restrict__ wb,         // f16 [OPAD][QTOT] permuted
    const float* __restrict__ b2,
    const short* __restrict__ tayl,       // f16 [48][NPTS] (this layer)
    const int* __restrict__ idx,
    float* __restrict__ pfout, int pfbstride,
    short* __restrict__ ftout, int CPADN) {
  constexpr int QTOT = CPAD * 48;
  constexpr int OUTER = QTOT / 64;
  constexpr int NJ = OTILE / 64;          // 1: R9 path, 2: k-split path
  constexpr int NJC = (NJ == 2) ? 4 : 1;  // B frags per wave
  constexpr int NH = OTILE / 32;          // dma calls per A buffer
  __shared__ __align__(16) short As[2][OTILE * 64];
  __shared__ __align__(16) short Bs[2][64 * 64];
  __shared__ __align__(16) unsigned short tayH[48 * 64];
  __shared__ int idxS[16 * 64];
  const int t = threadIdx.x;
  const int pbase = blockIdx.x * 64;
  const int obase = blockIdx.y * OTILE;
  const int b = pbase >> 12;
  const int nbase = pbase & (NN - 1);
  const int p_loc = t >> 2;
  const int sub = t & 3;
  // ---- stage f16 tay tile [48][64] + neighbor byte-offsets ----
#pragma unroll
  for (int i = 0; i < 3; ++i) {
    const int f = i * 1024 + t * 4;
    *(ushort4*)&tayH[f] =
        *(const ushort4*)&tayl[(size_t)(f >> 6) * NPTS + pbase + (f & 63)];
  }
  {
    const int4 mi = *(const int4*)&idx[(size_t)(pbase + p_loc) * KK + sub * 4];
    const int gb = b << 12;
    idxS[(sub * 4 + 0) * 64 + p_loc] = (gb + mi.x) << (LOGC + 1);
    idxS[(sub * 4 + 1) * 64 + p_loc] = (gb + mi.y) << (LOGC + 1);
    idxS[(sub * 4 + 2) * 64 + p_loc] = (gb + mi.z) << (LOGC + 1);
    idxS[(sub * 4 + 3) * 64 + p_loc] = (gb + mi.w) << (LOGC + 1);
  }
  // ---- A dma lane setup (source permutation implements the XOR swizzle) ----
  const int arow = t >> 3;                 // 0..31
  const int apos = t & 7;                  // stored chunk position
  const int aswz = (t >> 4) & 7;           // (row>>1)&7
  const short* awl[NH];
#pragma unroll
  for (int h = 0; h < NH; ++h)
    awl[h] = wb + (size_t)(obase + h * 32 + arow) * QTOT + ((apos ^ aswz) * 8);
  auto dmaA = [&](int o, int ph) {
#pragma unroll
    for (int h = 0; h < NH; ++h)
      __builtin_amdgcn_global_load_lds(
          (const __attribute__((address_space(1))) u32*)(awl[h] + o * 64),
          (__attribute__((address_space(3))) u32*)&As[ph][h * 2048 + t * 8], 16, 0, 0);
  };
  // ---- wave mapping ----
  const int lane = t & 63;
  const int w = t >> 6;
  const int wm = (NJ == 2) ? (w & 1) : 0;   // o-half
  const int ksw = (NJ == 2) ? (w >> 1) : 0; // k-half (NJ==2 only)
  const int wn = (NJ == 2) ? 0 : w;         // p-sixteenth (NJ==1 only)
  const int fr = lane & 15;
  const int fk = lane >> 4;
  const int rsw = (fr >> 1) & 7;           // frag-read un-swizzle (valid for A and B rows)
  const int bswz = (p_loc >> 1) & 7;       // build-write swizzle
  f32x4 acc[4][NJC];
#pragma unroll
  for (int i = 0; i < 4; ++i)
#pragma unroll
    for (int j = 0; j < NJC; ++j) acc[i][j] = (f32x4)(0.0f);

  uint4 fv[2];
  unsigned short tvh[2];
  auto prefB = [&](int o) {
#pragma unroll
    for (int z = 0; z < 2; ++z) {
      const int q0 = o * 64 + z * 32 + sub * 8;
      const int kq = q0 >> LOGC;
      const int c0 = q0 & (CPAD - 1);
      const int moff = idxS[(kq & 15) * 64 + p_loc];
      tvh[z] = tayH[kq * 64 + p_loc];
      fv[z] = *(const uint4*)(ftin + moff + (c0 << 1));
    }
  };
  auto buildB = [&](int ph) {
#pragma unroll
    for (int z = 0; z < 2; ++z) {
      const __half2 t2 = __half2half2(__ushort_as_half(tvh[z]));
      const uint4 f = fv[z];
      uint4 r;
      r.x = mulh2(f.x, t2); r.y = mulh2(f.y, t2);
      r.z = mulh2(f.z, t2); r.w = mulh2(f.w, t2);
      const int pos = (z * 4 + sub) ^ bswz;
      *(uint4*)&Bs[ph][p_loc * 64 + pos * 8] = r;
    }
  };
  // ---- prologue ----
  dmaA(0, 0);
  __syncthreads();            // tayH/idxS visible; dma0 drained
  prefB(0);
  buildB(0);
  __syncthreads();            // Bs[0] visible
#pragma unroll 1
  for (int o = 0; o < OUTER; ++o) {
    const int ph = o & 1;
    if (o + 1 < OUTER) { dmaA(o + 1, ph ^ 1); prefB(o + 1); }
    if constexpr (NJ == 2) {
      // k-split: this wave consumes only its k-half (ksw) of the outer
      f16x8 af[4], bf[4];
      const int pos8 = ((ksw * 4 + fk) ^ rsw) * 8;
#pragma unroll
      for (int i = 0; i < 4; ++i)
        af[i] = *(const f16x8*)&As[ph][(wm * 64 + i * 16 + fr) * 64 + pos8];
#pragma unroll
      for (int j = 0; j < 4; ++j)
        bf[j] = *(const f16x8*)&Bs[ph][(j * 16 + fr) * 64 + pos8];
      if (o + 1 < OUTER) buildB(ph ^ 1);
#pragma unroll
      for (int i = 0; i < 4; ++i)
#pragma unroll
        for (int j = 0; j < 4; ++j)
          acc[i][j] = __builtin_amdgcn_mfma_f32_16x16x32_f16(af[i], bf[j], acc[i][j], 0, 0, 0);
    } else {
#pragma unroll
      for (int z = 0; z < 2; ++z) {
        f16x8 af[4], bf;
        const int pos8 = ((z * 4 + fk) ^ rsw) * 8;
#pragma unroll
        for (int i = 0; i < 4; ++i)
          af[i] = *(const f16x8*)&As[ph][(i * 16 + fr) * 64 + pos8];
        bf = *(const f16x8*)&Bs[ph][(wn * 16 + fr) * 64 + pos8];
        if (z == 0 && o + 1 < OUTER) buildB(ph ^ 1);
#pragma unroll
        for (int i = 0; i < 4; ++i)
          acc[i][0] = __builtin_amdgcn_mfma_f32_16x16x32_f16(af[i], bf, acc[i][0], 0, 0, 0);
      }
    }
    if (o + 1 < OUTER) __syncthreads();  // As/Bs[ph] reads done; dma(o+1) drained
  }
  // ---- k-split reduction (NJ==2): merge ks-pair partial sums via As scratch ----
  if constexpr (NJ == 2) {
    __syncthreads();  // all frag reads done; As reusable as 32 KB f32 scratch
    float* red = (float*)(&As[0][0]) + wm * 4096;
    if (ksw == 1) {
#pragma unroll
      for (int i = 0; i < 4; ++i)
#pragma unroll
        for (int j = 0; j < 4; ++j)
#pragma unroll
          for (int r = 0; r < 4; ++r)
            red[((i * 4 + j) * 4 + r) * 64 + lane] = acc[i][j][r];
    }
    __syncthreads();
    if (ksw == 1) return;
#pragma unroll
    for (int i = 0; i < 4; ++i)
#pragma unroll
      for (int j = 0; j < 4; ++j)
#pragma unroll
        for (int r = 0; r < 4; ++r)
          acc[i][j][r] += red[((i * 4 + j) * 4 + r) * 64 + lane];
  }
  // ---- epilogue: bias + relu; fp32 -> pf, f16 -> ft_next ----
  float* outb = pfout + (size_t)b * pfbstride;
#pragma unroll
  for (int i = 0; i < 4; ++i) {
    const int o0 = obase + wm * 64 + i * 16 + fk * 4;
    if (o0 < COUT) {
      const float4 b4 = *(const float4*)&b2[o0];
#pragma unroll
      for (int j = 0; j < NJC; ++j) {
        const int p_l = (NJ == 2) ? (j * 16 + fr) : (wn * 16 + fr);
        const float v0 = fmaxf(acc[i][j][0] + b4.x, 0.0f);
        const float v1 = fmaxf(acc[i][j][1] + b4.y, 0.0f);
        const float v2 = fmaxf(acc[i][j][2] + b4.z, 0.0f);
        const float v3 = fmaxf(acc[i][j][3] + b4.w, 0.0f);
        outb[(size_t)(o0 + 0) * NN + nbase + p_l] = v0;
        outb[(size_t)(o0 + 1) * NN + nbase + p_l] = v1;
        outb[(size_t)(o0 + 2) * NN + nbase + p_l] = v2;
        outb[(size_t)(o0 + 3) * NN + nbase + p_l] = v3;
        if (ftout) {
          const __half2 h01 = __floats2half2_rn(v0, v1);
          const __half2 h23 = __floats2half2_rn(v2, v3);
          uint2 pk;
          pk.x = *(const u32*)&h01;
          pk.y = *(const u32*)&h23;
          *(uint2*)&ftout[(size_t)(pbase + p_l) * CPADN + o0] = pk;
        }
      }
    }
  }
}

// ---------------- top-2 over N per (b, channel) ----------------
__global__ __launch_bounds__(256) void top2_kernel(const float* __restrict__ pf,
                                                   float* __restrict__ cat) {
  const int row = blockIdx.x;  // b*480 + ch
  const float* p = pf + (size_t)row * NN;
  float m1 = -FLT_MAX, m2 = -FLT_MAX;
  for (int i = threadIdx.x; i < NN; i += 256) {
    const float v = p[i];
    if (v > m1) { m2 = m1; m1 = v; }
    else if (v > m2) m2 = v;
  }
#pragma unroll
  for (int off = 32; off > 0; off >>= 1) {
    const float o1 = __shfl_down(m1, off, 64);
    const float o2 = __shfl_down(m2, off, 64);
    const float nm1 = fmaxf(m1, o1);
    const float nm2 = fmaxf(fminf(m1, o1), fmaxf(m2, o2));
    m1 = nm1; m2 = nm2;
  }
  __shared__ float s1[4], s2[4];
  const int wid = threadIdx.x >> 6;
  if ((threadIdx.x & 63) == 0) { s1[wid] = m1; s2[wid] = m2; }
  __syncthreads();
  if (threadIdx.x == 0) {
    m1 = s1[0]; m2 = s2[0];
#pragma unroll
    for (int w = 1; w < 4; ++w) {
      const float o1 = s1[w], o2 = s2[w];
      const float nm1 = fmaxf(m1, o1);
      const float nm2 = fmaxf(fminf(m1, o1), fmaxf(m2, o2));
      m1 = nm1; m2 = nm2;
    }
    const int b = row / 480, ch = row % 480;
    cat[b * 960 + ch * 2 + 0] = m1;
    cat[b * 960 + ch * 2 + 1] = m2;
  }
}

extern "C" void kernel_launch(void* const* d_in, const int* in_sizes, int n_in,
                              void* d_out, int out_size, void* d_ws, size_t ws_size,
                              hipStream_t stream) {
  const float* pc = (const float*)d_in[0];
  const float* w1s[4]; const float* b1s[4]; const float* w2s[4]; const float* b2s[4];
  for (int l = 0; l < 4; ++l) {
    w1s[l] = (const float*)d_in[1 + 4 * l];
    b1s[l] = (const float*)d_in[2 + 4 * l];
    w2s[l] = (const float*)d_in[3 + 4 * l];
    b2s[l] = (const float*)d_in[4 + 4 * l];
  }
  // ---- workspace layout (bytes) ----
  char* W = (char*)d_ws;
  int* idx = (int*)W;                                  // 1,048,576
  short* tayh = (short*)(W + 1048576);                 // 4 x 1,572,864 = 6,291,456 (f16)
  short* wb1 = (short*)(W + 13631488);                 // 64*384    f16 =    49,152 B
  short* wb2 = wb1 + 64 * 384;                         // 64*1536       =   196,608 B
  short* wb3 = wb2 + 64 * 1536;                        // 128*3072      =   786,432 B
  short* wb4 = wb3 + 128 * 3072;                       // 256*6144      = 3,145,728 B
  short* ft0 = (short*)(W + 17809408);                 // 16384*8  f16  =   262,144 B
  short* ft1 = (short*)(W + 18071552);                 // 16384*32      = 1,048,576 B
  // knn-phase alias (consumed before taylor writes):
  float4* xyzq = (float4*)(W + 1048576);               // 262,144 B, in tayh[0]
  // conv-phase aliases (placed after the 6.29 MB live tayh region):
  short* ft2 = (short*)(W + 1048576 + 6291456);        // 1 MB, written L2-epi
  short* ft3 = (short*)(W + 1048576 + 6291456 + 1048576);  // 2 MB, written L3-epi
  float* cat = (float*)d_out;                          // B*960
  float* pf = (float*)d_out + BB * 960;                // (B, 480, N)
  const int pfstride = 480 * NN;

  pc2ft_kernel<<<dim3(NPTS / 256), 256, 0, stream>>>(pc, ft0, xyzq);
  knn_select<<<dim3(NPTS), 256, 0, stream>>>(xyzq, idx);
  wcvt_kernel<<<dim3((64 * 384 / 8 + 255) / 256), 256, 0, stream>>>(w2s[0], wb1, 6, 32, 8, 3, 64 * 384 / 8);
  wcvt_kernel<<<dim3((64 * 1536 / 8 + 255) / 256), 256, 0, stream>>>(w2s[1], wb2, 32, 64, 32, 5, 64 * 1536 / 8);
  wcvt_kernel<<<dim3((128 * 3072 / 8 + 255) / 256), 256, 0, stream>>>(w2s[2], wb3, 64, 128, 64, 6, 128 * 3072 / 8);
  wcvt_kernel<<<dim3((256 * 6144 / 8 + 255) / 256), 256, 0, stream>>>(w2s[3], wb4, 128, 256, 128, 7, 256 * 6144 / 8);
  taylor_kernel<<<dim3(NPTS * KK / 256), 256, 0, stream>>>(
      pc, idx, w1s[0], b1s[0], w1s[1], b1s[1], w1s[2], b1s[2], w1s[3], b1s[3], tayh);
  conv_mfma_kernel<8, 3, 32, 64><<<dim3(NPTS / 64, 1), 256, 0, stream>>>(
      (const char*)ft0, wb1, b2s[0], tayh + 0 * (size_t)NT48, idx,
      pf + (size_t)0 * NN, pfstride, ft1, 32);
  conv_mfma_kernel<32, 5, 64, 64><<<dim3(NPTS / 64, 1), 256, 0, stream>>>(
      (const char*)ft1, wb2, b2s[1], tayh + 1 * (size_t)NT48, idx,
      pf + (size_t)32 * NN, pfstride, ft2, 64);
  conv_mfma_kernel<64, 6, 128, 64><<<dim3(NPTS / 64, 2), 256, 0, stream>>>(
      (const char*)ft2, wb3, b2s[2], tayh + 2 * (size_t)NT48, idx,
      pf + (size_t)96 * NN, pfstride, ft3, 128);
  conv_mfma_kernel<128, 7, 256, 128><<<dim3(NPTS / 64, 2), 256, 0, stream>>>(
      (const char*)ft3, wb4, b2s[3], tayh + 3 * (size_t)NT48, idx,
      pf + (size_t)224 * NN, pfstride, nullptr, 0);
  top2_kernel<<<dim3(BB * 480), 256, 0, stream>>>(pf, cat);
}

// Round 13
// 335.423 us; speedup vs baseline: 1.7962x; 1.0643x over previous
//
#include <hip/hip_runtime.h>
#include <hip/hip_fp16.h>
#include <cfloat>

#define BB 4
#define NN 4096
#define KK 16
#define NPTS (BB * NN)      // 16384
#define NT48 (48 * NPTS)    // per-layer tay f16 elements, layout [48][NPTS]

typedef __attribute__((ext_vector_type(8))) _Float16 f16x8;
typedef __attribute__((ext_vector_type(4))) float f32x4;
typedef unsigned int u32;
typedef unsigned long long u64;

__device__ __forceinline__ short f2h(float v) {
  __half h = __float2half_rn(v);
  return __half_as_short(h);
}
__device__ __forceinline__ u32 mulh2(u32 a, __half2 t) {
  __half2 x = __hmul2(*(__half2*)&a, t);
  return *(u32*)&x;
}

// ---------------- weights fp32 (o,(c,t),k) -> f16 permuted [o][(t,k,c)] padded ----------------
__device__ __forceinline__ void wcvt_body(const float* __restrict__ w2,
                                          short* __restrict__ wb,
                                          int CIN, int COUT, int CPAD, int LOGC,
                                          int total8, int i) {
  if (i >= total8) return;
  const int q8 = i * 8;
  const int QT = CPAD * 48;
  const int o = q8 / QT;
  const int r = q8 - o * QT;
  const int kq = r >> LOGC;
  const int c0 = r & (CPAD - 1);
  const int tt = kq >> 4;
  const int k = kq & 15;
  short h[8];
#pragma unroll
  for (int j = 0; j < 8; ++j) {
    const int c = c0 + j;
    const float v = (o < COUT && c < CIN) ? w2[(size_t)o * CIN * 48 + (c * 3 + tt) * 16 + k] : 0.0f;
    h[j] = f2h(v);
  }
  short* d = wb + (size_t)o * QT + r;
#pragma unroll
  for (int j = 0; j < 8; ++j) d[j] = h[j];
}

// ---------------- fused prep: pc2ft + xyzq + all 4 weight converts ----------------
// blocks [0,64): pc -> ft0 f16 [p][8] + xyzq f32 [p][4]
// blocks [64,1084): weight conversion, region-dispatched per layer.
__global__ __launch_bounds__(256) void prep_kernel(
    const float* __restrict__ pc, short* __restrict__ ft0, float4* __restrict__ xyzq,
    const float* __restrict__ w2_1, short* __restrict__ wb1,
    const float* __restrict__ w2_2, short* __restrict__ wb2,
    const float* __restrict__ w2_3, short* __restrict__ wb3,
    const float* __restrict__ w2_4, short* __restrict__ wb4) {
  const int blk = blockIdx.x;
  const int t = threadIdx.x;
  if (blk < 64) {
    const int i = blk * 256 + t;
    const float* s = pc + (size_t)i * 6;
    short* d = ft0 + (size_t)i * 8;
#pragma unroll
    for (int c = 0; c < 6; ++c) d[c] = f2h(s[c]);
    d[6] = 0; d[7] = 0;
    const float x = s[0], y = s[1], z = s[2];
    xyzq[i] = make_float4(x, y, z, fmaf(z, z, fmaf(y, y, x * x)));
  } else if (blk < 76) {
    wcvt_body(w2_1, wb1, 6, 32, 8, 3, 3072, (blk - 64) * 256 + t);
  } else if (blk < 124) {
    wcvt_body(w2_2, wb2, 32, 64, 32, 5, 12288, (blk - 76) * 256 + t);
  } else if (blk < 316) {
    wcvt_body(w2_3, wb3, 64, 128, 64, 6, 49152, (blk - 124) * 256 + t);
  } else {
    wcvt_body(w2_4, wb4, 128, 256, 128, 7, 196608, (blk - 316) * 256 + t);
  }
}

// ---------------- KNN: min-threshold select, TWO queries per block ----------------
// Both queries share the candidate float4 loads (halves L1/L2 read traffic).
// Per-query algorithm identical to the verified single-query version:
// T = min over waves of (16th-smallest of 64 thread-mins) >= true d2_16;
// collect d2<=T; rank-based extraction in exact (d2, idx) lexicographic order.
__global__ __launch_bounds__(256) void knn_select2(const float4* __restrict__ xyzq,
                                                   int* __restrict__ idx_out) {
  __shared__ float wT[2][4];
  __shared__ u64 list[2][128];
  __shared__ int lcnt[2];
  const int g0 = blockIdx.x * 2;   // queries g0, g0+1 (same batch: NN is even)
  const int b = g0 >> 12;
  const int t = threadIdx.x;
  const int lane = t & 63;
  const float4* base = xyzq + (b << 12);
  const float4 qa = xyzq[g0];
  const float4 qb = xyzq[g0 + 1];
  float da[16], db[16];
  float mina = FLT_MAX, minb = FLT_MAX;
#pragma unroll
  for (int i = 0; i < 16; ++i) {
    const float4 c = base[i * 256 + t];
    const float dota = fmaf(qa.z, c.z, fmaf(qa.y, c.y, qa.x * c.x));
    da[i] = fmaf(-2.0f, dota, qa.w + c.w);
    mina = fminf(mina, da[i]);
    const float dotb = fmaf(qb.z, c.z, fmaf(qb.y, c.y, qb.x * c.x));
    db[i] = fmaf(-2.0f, dotb, qb.w + c.w);
    minb = fminf(minb, db[i]);
  }
  if (t < 2) lcnt[t] = 0;
  // ---- in-wave bitonic sort (ascending) of 64 thread-mins, both queries ----
  float va = mina, vb = minb;
#pragma unroll
  for (int k = 2; k <= 64; k <<= 1) {
#pragma unroll
    for (int j = k >> 1; j >= 1; j >>= 1) {
      const float oa = __shfl_xor(va, j, 64);
      const float ob = __shfl_xor(vb, j, 64);
      const bool take_min = (((lane & k) == 0) == ((lane & j) == 0));
      va = take_min ? fminf(va, oa) : fmaxf(va, oa);
      vb = take_min ? fminf(vb, ob) : fmaxf(vb, ob);
    }
  }
  const float twa = __shfl(va, 15, 64);  // 16th smallest in this wave
  const float twb = __shfl(vb, 15, 64);
  if (lane == 0) { wT[0][t >> 6] = twa; wT[1][t >> 6] = twb; }
  __syncthreads();  // covers wT + lcnt
  const float Ta = fminf(fminf(wT[0][0], wT[0][1]), fminf(wT[0][2], wT[0][3]));
  const float Tb = fminf(fminf(wT[1][0], wT[1][1]), fminf(wT[1][2], wT[1][3]));
  // ---- collect candidates (superset of each top-16) ----
#pragma unroll
  for (int i = 0; i < 16; ++i) {
    if (da[i] <= Ta) {
      const u32 bits = __float_as_uint(da[i]);
      const u32 key = bits ^ ((u32)((int)bits >> 31) | 0x80000000u);
      const int pos = atomicAdd(&lcnt[0], 1);
      if (pos < 128) list[0][pos] = ((u64)key << 32) | (u32)(i * 256 + t);
    }
    if (db[i] <= Tb) {
      const u32 bits = __float_as_uint(db[i]);
      const u32 key = bits ^ ((u32)((int)bits >> 31) | 0x80000000u);
      const int pos = atomicAdd(&lcnt[1], 1);
      if (pos < 128) list[1][pos] = ((u64)key << 32) | (u32)(i * 256 + t);
    }
  }
  __syncthreads();
  // ---- rank-based extraction, both queries ----
  if (t < 128) {
#pragma unroll
    for (int qq = 0; qq < 2; ++qq) {
      const int m = min(lcnt[qq], 128);
      const u64 my = (t < m) ? list[qq][t] : ~0ull;
      int rank = 0;
#pragma unroll 4
      for (int i = 0; i < m; ++i) rank += (list[qq][i] < my) ? 1 : 0;
      if (t < m && rank < 16)
        idx_out[(size_t)(g0 + qq) * KK + rank] = (int)(my & 0xFFFFFFFFull);
    }
  }
}

// ---------------- tay_h[l][t*16+k][p] = f16(w1_l @ taylor(rel) + b1_l) ----------------
__global__ __launch_bounds__(256) void taylor_kernel(
    const float* __restrict__ pc, const int* __restrict__ idx,
    const float* __restrict__ w1_1, const float* __restrict__ b1_1,
    const float* __restrict__ w1_2, const float* __restrict__ b1_2,
    const float* __restrict__ w1_3, const float* __restrict__ b1_3,
    const float* __restrict__ w1_4, const float* __restrict__ b1_4,
    short* __restrict__ tayh) {
  const int i = blockIdx.x * 256 + threadIdx.x;  // p fastest, then k
  if (i >= NPTS * KK) return;
  const int p = i & (NPTS - 1);
  const int k = i >> 14;
  const int n = p & (NN - 1);
  const int b = p >> 12;
  const float* pcb = pc + (size_t)b * NN * 6;
  const int m = idx[(size_t)p * KK + k];
  const float x = pcb[m * 6 + 0] - pcb[n * 6 + 0];
  const float y = pcb[m * 6 + 1] - pcb[n * 6 + 1];
  const float z = pcb[m * 6 + 2] - pcb[n * 6 + 2];
  float tb[20];
  tb[0] = 1.0f; tb[1] = x; tb[2] = y; tb[3] = z;
  tb[4] = x * x; tb[5] = x * y; tb[6] = x * z;
  tb[7] = y * y; tb[8] = y * z; tb[9] = z * z;
  tb[10] = tb[4] * x; tb[11] = tb[4] * y; tb[12] = tb[4] * z;
  tb[13] = tb[5] * y; tb[14] = tb[5] * z; tb[15] = tb[6] * z;
  tb[16] = tb[7] * y; tb[17] = tb[7] * z; tb[18] = tb[8] * z; tb[19] = tb[9] * z;
  const float* w1s[4] = {w1_1, w1_2, w1_3, w1_4};
  const float* b1s[4] = {b1_1, b1_2, b1_3, b1_4};
#pragma unroll
  for (int l = 0; l < 4; ++l) {
    const float* w1 = w1s[l];
    const float* b1 = b1s[l];
#pragma unroll
    for (int c = 0; c < 3; ++c) {
      float s = b1[c];
#pragma unroll
      for (int j = 0; j < 20; ++j) s = fmaf(w1[c * 20 + j], tb[j], s);
      tayh[(size_t)(l * 48 + c * 16 + k) * NPTS + p] = f2h(s);
    }
  }
}

// ---------------- spider conv via f16 MFMA; A+B in LDS (R12 structure, unchanged) ----------------
// OTILE=64 (L1-L3): wave = 64o x 16p. OTILE=128 (L4): k-split, wave = 64o x 64p
// x half-K; ks-pairs merge partial sums via end-of-kernel LDS reduction.
template <int CPAD, int LOGC, int COUT, int OTILE>
__global__ __launch_bounds__(256) void conv_mfma_kernel(
    const char* __restrict__ ftin,        // f16 [NPTS][CPAD]
    const short* __restrict__ wb,         // f16 [OPAD][QTOT] permuted
    const float* __restrict__ b2,
    const short* __restrict__ tayl,       // f16 [48][NPTS] (this layer)
    const int* __restrict__ idx,
    float* __restrict__ pfout, int pfbstride,
    short* __restrict__ ftout, int CPADN) {
  constexpr int QTOT = CPAD * 48;
  constexpr int OUTER = QTOT / 64;
  constexpr int NJ = OTILE / 64;          // 1: base path, 2: k-split path
  constexpr int NJC = (NJ == 2) ? 4 : 1;  // B frags per wave
  constexpr int NH = OTILE / 32;          // dma calls per A buffer
  __shared__ __align__(16) short As[2][OTILE * 64];
  __shared__ __align__(16) short Bs[2][64 * 64];
  __shared__ __align__(16) unsigned short tayH[48 * 64];
  __shared__ int idxS[16 * 64];
  const int t = threadIdx.x;
  const int pbase = blockIdx.x * 64;
  const int obase = blockIdx.y * OTILE;
  const int b = pbase >> 12;
  const int nbase = pbase & (NN - 1);
  const int p_loc = t >> 2;
  const int sub = t & 3;
  // ---- stage f16 tay tile [48][64] + neighbor byte-offsets ----
#pragma unroll
  for (int i = 0; i < 3; ++i) {
    const int f = i * 1024 + t * 4;
    *(ushort4*)&tayH[f] =
        *(const ushort4*)&tayl[(size_t)(f >> 6) * NPTS + pbase + (f & 63)];
  }
  {
    const int4 mi = *(const int4*)&idx[(size_t)(pbase + p_loc) * KK + sub * 4];
    const int gb = b << 12;
    idxS[(sub * 4 + 0) * 64 + p_loc] = (gb + mi.x) << (LOGC + 1);
    idxS[(sub * 4 + 1) * 64 + p_loc] = (gb + mi.y) << (LOGC + 1);
    idxS[(sub * 4 + 2) * 64 + p_loc] = (gb + mi.z) << (LOGC + 1);
    idxS[(sub * 4 + 3) * 64 + p_loc] = (gb + mi.w) << (LOGC + 1);
  }
  // ---- A dma lane setup (source permutation implements the XOR swizzle) ----
  const int arow = t >> 3;                 // 0..31
  const int apos = t & 7;                  // stored chunk position
  const int aswz = (t >> 4) & 7;           // (row>>1)&7
  const short* awl[NH];
#pragma unroll
  for (int h = 0; h < NH; ++h)
    awl[h] = wb + (size_t)(obase + h * 32 + arow) * QTOT + ((apos ^ aswz) * 8);
  auto dmaA = [&](int o, int ph) {
#pragma unroll
    for (int h = 0; h < NH; ++h)
      __builtin_amdgcn_global_load_lds(
          (const __attribute__((address_space(1))) u32*)(awl[h] + o * 64),
          (__attribute__((address_space(3))) u32*)&As[ph][h * 2048 + t * 8], 16, 0, 0);
  };
  // ---- wave mapping ----
  const int lane = t & 63;
  const int w = t >> 6;
  const int wm = (NJ == 2) ? (w & 1) : 0;   // o-half
  const int ksw = (NJ == 2) ? (w >> 1) : 0; // k-half (NJ==2 only)
  const int wn = (NJ == 2) ? 0 : w;         // p-sixteenth (NJ==1 only)
  const int fr = lane & 15;
  const int fk = lane >> 4;
  const int rsw = (fr >> 1) & 7;           // frag-read un-swizzle
  const int bswz = (p_loc >> 1) & 7;       // build-write swizzle
  f32x4 acc[4][NJC];
#pragma unroll
  for (int i = 0; i < 4; ++i)
#pragma unroll
    for (int j = 0; j < NJC; ++j) acc[i][j] = (f32x4)(0.0f);

  uint4 fv[2];
  unsigned short tvh[2];
  auto prefB = [&](int o) {
#pragma unroll
    for (int z = 0; z < 2; ++z) {
      const int q0 = o * 64 + z * 32 + sub * 8;
      const int kq = q0 >> LOGC;
      const int c0 = q0 & (CPAD - 1);
      const int moff = idxS[(kq & 15) * 64 + p_loc];
      tvh[z] = tayH[kq * 64 + p_loc];
      fv[z] = *(const uint4*)(ftin + moff + (c0 << 1));
    }
  };
  auto buildB = [&](int ph) {
#pragma unroll
    for (int z = 0; z < 2; ++z) {
      const __half2 t2 = __half2half2(__ushort_as_half(tvh[z]));
      const uint4 f = fv[z];
      uint4 r;
      r.x = mulh2(f.x, t2); r.y = mulh2(f.y, t2);
      r.z = mulh2(f.z, t2); r.w = mulh2(f.w, t2);
      const int pos = (z * 4 + sub) ^ bswz;
      *(uint4*)&Bs[ph][p_loc * 64 + pos * 8] = r;
    }
  };
  // ---- prologue ----
  dmaA(0, 0);
  __syncthreads();            // tayH/idxS visible; dma0 drained
  prefB(0);
  buildB(0);
  __syncthreads();            // Bs[0] visible
#pragma unroll 1
  for (int o = 0; o < OUTER; ++o) {
    const int ph = o & 1;
    if (o + 1 < OUTER) { dmaA(o + 1, ph ^ 1); prefB(o + 1); }
    if constexpr (NJ == 2) {
      f16x8 af[4], bf[4];
      const int pos8 = ((ksw * 4 + fk) ^ rsw) * 8;
#pragma unroll
      for (int i = 0; i < 4; ++i)
        af[i] = *(const f16x8*)&As[ph][(wm * 64 + i * 16 + fr) * 64 + pos8];
#pragma unroll
      for (int j = 0; j < 4; ++j)
        bf[j] = *(const f16x8*)&Bs[ph][(j * 16 + fr) * 64 + pos8];
      if (o + 1 < OUTER) buildB(ph ^ 1);
#pragma unroll
      for (int i = 0; i < 4; ++i)
#pragma unroll
        for (int j = 0; j < 4; ++j)
          acc[i][j] = __builtin_amdgcn_mfma_f32_16x16x32_f16(af[i], bf[j], acc[i][j], 0, 0, 0);
    } else {
#pragma unroll
      for (int z = 0; z < 2; ++z) {
        f16x8 af[4], bf;
        const int pos8 = ((z * 4 + fk) ^ rsw) * 8;
#pragma unroll
        for (int i = 0; i < 4; ++i)
          af[i] = *(const f16x8*)&As[ph][(i * 16 + fr) * 64 + pos8];
        bf = *(const f16x8*)&Bs[ph][(wn * 16 + fr) * 64 + pos8];
        if (z == 0 && o + 1 < OUTER) buildB(ph ^ 1);
#pragma unroll
        for (int i = 0; i < 4; ++i)
          acc[i][0] = __builtin_amdgcn_mfma_f32_16x16x32_f16(af[i], bf, acc[i][0], 0, 0, 0);
      }
    }
    if (o + 1 < OUTER) __syncthreads();
  }
  // ---- k-split reduction (NJ==2): merge ks-pair partial sums via As scratch ----
  if constexpr (NJ == 2) {
    __syncthreads();
    float* red = (float*)(&As[0][0]) + wm * 4096;
    if (ksw == 1) {
#pragma unroll
      for (int i = 0; i < 4; ++i)
#pragma unroll
        for (int j = 0; j < 4; ++j)
#pragma unroll
          for (int r = 0; r < 4; ++r)
            red[((i * 4 + j) * 4 + r) * 64 + lane] = acc[i][j][r];
    }
    __syncthreads();
    if (ksw == 1) return;
#pragma unroll
    for (int i = 0; i < 4; ++i)
#pragma unroll
      for (int j = 0; j < 4; ++j)
#pragma unroll
        for (int r = 0; r < 4; ++r)
          acc[i][j][r] += red[((i * 4 + j) * 4 + r) * 64 + lane];
  }
  // ---- epilogue: bias + relu; fp32 -> pf, f16 -> ft_next ----
  float* outb = pfout + (size_t)b * pfbstride;
#pragma unroll
  for (int i = 0; i < 4; ++i) {
    const int o0 = obase + wm * 64 + i * 16 + fk * 4;
    if (o0 < COUT) {
      const float4 b4 = *(const float4*)&b2[o0];
#pragma unroll
      for (int j = 0; j < NJC; ++j) {
        const int p_l = (NJ == 2) ? (j * 16 + fr) : (wn * 16 + fr);
        const float v0 = fmaxf(acc[i][j][0] + b4.x, 0.0f);
        const float v1 = fmaxf(acc[i][j][1] + b4.y, 0.0f);
        const float v2 = fmaxf(acc[i][j][2] + b4.z, 0.0f);
        const float v3 = fmaxf(acc[i][j][3] + b4.w, 0.0f);
        outb[(size_t)(o0 + 0) * NN + nbase + p_l] = v0;
        outb[(size_t)(o0 + 1) * NN + nbase + p_l] = v1;
        outb[(size_t)(o0 + 2) * NN + nbase + p_l] = v2;
        outb[(size_t)(o0 + 3) * NN + nbase + p_l] = v3;
        if (ftout) {
          const __half2 h01 = __floats2half2_rn(v0, v1);
          const __half2 h23 = __floats2half2_rn(v2, v3);
          uint2 pk;
          pk.x = *(const u32*)&h01;
          pk.y = *(const u32*)&h23;
          *(uint2*)&ftout[(size_t)(pbase + p_l) * CPADN + o0] = pk;
        }
      }
    }
  }
}

// ---------------- top-2 over N per (b, channel) ----------------
__global__ __launch_bounds__(256) void top2_kernel(const float* __restrict__ pf,
                                                   float* __restrict__ cat) {
  const int row = blockIdx.x;  // b*480 + ch
  const float* p = pf + (size_t)row * NN;
  float m1 = -FLT_MAX, m2 = -FLT_MAX;
  for (int i = threadIdx.x; i < NN; i += 256) {
    const float v = p[i];
    if (v > m1) { m2 = m1; m1 = v; }
    else if (v > m2) m2 = v;
  }
#pragma unroll
  for (int off = 32; off > 0; off >>= 1) {
    const float o1 = __shfl_down(m1, off, 64);
    const float o2 = __shfl_down(m2, off, 64);
    const float nm1 = fmaxf(m1, o1);
    const float nm2 = fmaxf(fminf(m1, o1), fmaxf(m2, o2));
    m1 = nm1; m2 = nm2;
  }
  __shared__ float s1[4], s2[4];
  const int wid = threadIdx.x >> 6;
  if ((threadIdx.x & 63) == 0) { s1[wid] = m1; s2[wid] = m2; }
  __syncthreads();
  if (threadIdx.x == 0) {
    m1 = s1[0]; m2 = s2[0];
#pragma unroll
    for (int w = 1; w < 4; ++w) {
      const float o1 = s1[w], o2 = s2[w];
      const float nm1 = fmaxf(m1, o1);
      const float nm2 = fmaxf(fminf(m1, o1), fmaxf(m2, o2));
      m1 = nm1; m2 = nm2;
    }
    const int b = row / 480, ch = row % 480;
    cat[b * 960 + ch * 2 + 0] = m1;
    cat[b * 960 + ch * 2 + 1] = m2;
  }
}

extern "C" void kernel_launch(void* const* d_in, const int* in_sizes, int n_in,
                              void* d_out, int out_size, void* d_ws, size_t ws_size,
                              hipStream_t stream) {
  const float* pc = (const float*)d_in[0];
  const float* w1s[4]; const float* b1s[4]; const float* w2s[4]; const float* b2s[4];
  for (int l = 0; l < 4; ++l) {
    w1s[l] = (const float*)d_in[1 + 4 * l];
    b1s[l] = (const float*)d_in[2 + 4 * l];
    w2s[l] = (const float*)d_in[3 + 4 * l];
    b2s[l] = (const float*)d_in[4 + 4 * l];
  }
  // ---- workspace layout (bytes) ----
  char* W = (char*)d_ws;
  int* idx = (int*)W;                                  // 1,048,576
  short* tayh = (short*)(W + 1048576);                 // 4 x 1,572,864 = 6,291,456 (f16)
  short* wb1 = (short*)(W + 13631488);                 // 64*384    f16 =    49,152 B
  short* wb2 = wb1 + 64 * 384;                         // 64*1536       =   196,608 B
  short* wb3 = wb2 + 64 * 1536;                        // 128*3072      =   786,432 B
  short* wb4 = wb3 + 128 * 3072;                       // 256*6144      = 3,145,728 B
  short* ft0 = (short*)(W + 17809408);                 // 16384*8  f16  =   262,144 B
  short* ft1 = (short*)(W + 18071552);                 // 16384*32      = 1,048,576 B
  // knn-phase alias (consumed before taylor writes):
  float4* xyzq = (float4*)(W + 1048576);               // 262,144 B, in tayh[0]
  // conv-phase aliases (placed after the 6.29 MB live tayh region):
  short* ft2 = (short*)(W + 1048576 + 6291456);        // 1 MB, written L2-epi
  short* ft3 = (short*)(W + 1048576 + 6291456 + 1048576);  // 2 MB, written L3-epi
  float* cat = (float*)d_out;                          // B*960
  float* pf = (float*)d_out + BB * 960;                // (B, 480, N)
  const int pfstride = 480 * NN;

  prep_kernel<<<dim3(1084), 256, 0, stream>>>(
      pc, ft0, xyzq, w2s[0], wb1, w2s[1], wb2, w2s[2], wb3, w2s[3], wb4);
  knn_select2<<<dim3(NPTS / 2), 256, 0, stream>>>(xyzq, idx);
  taylor_kernel<<<dim3(NPTS * KK / 256), 256, 0, stream>>>(
      pc, idx, w1s[0], b1s[0], w1s[1], b1s[1], w1s[2], b1s[2], w1s[3], b1s[3], tayh);
  conv_mfma_kernel<8, 3, 32, 64><<<dim3(NPTS / 64, 1), 256, 0, stream>>>(
      (const char*)ft0, wb1, b2s[0], tayh + 0 * (size_t)NT48, idx,
      pf + (size_t)0 * NN, pfstride, ft1, 32);
  conv_mfma_kernel<32, 5, 64, 64><<<dim3(NPTS / 64, 1), 256, 0, stream>>>(
      (const char*)ft1, wb2, b2s[1], tayh + 1 * (size_t)NT48, idx,
      pf + (size_t)32 * NN, pfstride, ft2, 64);
  conv_mfma_kernel<64, 6, 128, 64><<<dim3(NPTS / 64, 2), 256, 0, stream>>>(
      (const char*)ft2, wb3, b2s[2], tayh + 2 * (size_t)NT48, idx,
      pf + (size_t)96 * NN, pfstride, ft3, 128);
  conv_mfma_kernel<128, 7, 256, 128><<<dim3(NPTS / 64, 2), 256, 0, stream>>>(
      (const char*)ft3, wb4, b2s[3], tayh + 3 * (size_t)NT48, idx,
      pf + (size_t)224 * NN, pfstride, nullptr, 0);
  top2_kernel<<<dim3(BB * 480), 256, 0, stream>>>(pf, cat);
}

// Round 14
// 332.580 us; speedup vs baseline: 1.8116x; 1.0085x over previous
//
#include <hip/hip_runtime.h>
#include <hip/hip_fp16.h>
#include <cfloat>

#define BB 4
#define NN 4096
#define KK 16
#define NPTS (BB * NN)      // 16384

typedef __attribute__((ext_vector_type(8))) _Float16 f16x8;
typedef __attribute__((ext_vector_type(4))) float f32x4;
typedef unsigned int u32;
typedef unsigned long long u64;

__device__ __forceinline__ short f2h(float v) {
  __half h = __float2half_rn(v);
  return __half_as_short(h);
}
__device__ __forceinline__ u32 mulh2(u32 a, __half2 t) {
  __half2 x = __hmul2(*(__half2*)&a, t);
  return *(u32*)&x;
}

// ---------------- weights fp32 (o,(c,t),k) -> f16 permuted [o][(t,k,c)] padded ----------------
__device__ __forceinline__ void wcvt_body(const float* __restrict__ w2,
                                          short* __restrict__ wb,
                                          int CIN, int COUT, int CPAD, int LOGC,
                                          int total8, int i) {
  if (i >= total8) return;
  const int q8 = i * 8;
  const int QT = CPAD * 48;
  const int o = q8 / QT;
  const int r = q8 - o * QT;
  const int kq = r >> LOGC;
  const int c0 = r & (CPAD - 1);
  const int tt = kq >> 4;
  const int k = kq & 15;
  short h[8];
#pragma unroll
  for (int j = 0; j < 8; ++j) {
    const int c = c0 + j;
    const float v = (o < COUT && c < CIN) ? w2[(size_t)o * CIN * 48 + (c * 3 + tt) * 16 + k] : 0.0f;
    h[j] = f2h(v);
  }
  short* d = wb + (size_t)o * QT + r;
#pragma unroll
  for (int j = 0; j < 8; ++j) d[j] = h[j];
}

// ---------------- fused prep: pc2ft + xyzq + all 4 weight converts ----------------
__global__ __launch_bounds__(256) void prep_kernel(
    const float* __restrict__ pc, short* __restrict__ ft0, float4* __restrict__ xyzq,
    const float* __restrict__ w2_1, short* __restrict__ wb1,
    const float* __restrict__ w2_2, short* __restrict__ wb2,
    const float* __restrict__ w2_3, short* __restrict__ wb3,
    const float* __restrict__ w2_4, short* __restrict__ wb4) {
  const int blk = blockIdx.x;
  const int t = threadIdx.x;
  if (blk < 64) {
    const int i = blk * 256 + t;
    const float* s = pc + (size_t)i * 6;
    short* d = ft0 + (size_t)i * 8;
#pragma unroll
    for (int c = 0; c < 6; ++c) d[c] = f2h(s[c]);
    d[6] = 0; d[7] = 0;
    const float x = s[0], y = s[1], z = s[2];
    xyzq[i] = make_float4(x, y, z, fmaf(z, z, fmaf(y, y, x * x)));
  } else if (blk < 76) {
    wcvt_body(w2_1, wb1, 6, 32, 8, 3, 3072, (blk - 64) * 256 + t);
  } else if (blk < 124) {
    wcvt_body(w2_2, wb2, 32, 64, 32, 5, 12288, (blk - 76) * 256 + t);
  } else if (blk < 316) {
    wcvt_body(w2_3, wb3, 64, 128, 64, 6, 49152, (blk - 124) * 256 + t);
  } else {
    wcvt_body(w2_4, wb4, 128, 256, 128, 7, 196608, (blk - 316) * 256 + t);
  }
}

// ---------------- KNN: min-threshold select, TWO queries per block ----------------
__global__ __launch_bounds__(256) void knn_select2(const float4* __restrict__ xyzq,
                                                   int* __restrict__ idx_out) {
  __shared__ float wT[2][4];
  __shared__ u64 list[2][128];
  __shared__ int lcnt[2];
  const int g0 = blockIdx.x * 2;   // queries g0, g0+1 (same batch: NN is even)
  const int b = g0 >> 12;
  const int t = threadIdx.x;
  const int lane = t & 63;
  const float4* base = xyzq + (b << 12);
  const float4 qa = xyzq[g0];
  const float4 qb = xyzq[g0 + 1];
  float da[16], db[16];
  float mina = FLT_MAX, minb = FLT_MAX;
#pragma unroll
  for (int i = 0; i < 16; ++i) {
    const float4 c = base[i * 256 + t];
    const float dota = fmaf(qa.z, c.z, fmaf(qa.y, c.y, qa.x * c.x));
    da[i] = fmaf(-2.0f, dota, qa.w + c.w);
    mina = fminf(mina, da[i]);
    const float dotb = fmaf(qb.z, c.z, fmaf(qb.y, c.y, qb.x * c.x));
    db[i] = fmaf(-2.0f, dotb, qb.w + c.w);
    minb = fminf(minb, db[i]);
  }
  if (t < 2) lcnt[t] = 0;
  float va = mina, vb = minb;
#pragma unroll
  for (int k = 2; k <= 64; k <<= 1) {
#pragma unroll
    for (int j = k >> 1; j >= 1; j >>= 1) {
      const float oa = __shfl_xor(va, j, 64);
      const float ob = __shfl_xor(vb, j, 64);
      const bool take_min = (((lane & k) == 0) == ((lane & j) == 0));
      va = take_min ? fminf(va, oa) : fmaxf(va, oa);
      vb = take_min ? fminf(vb, ob) : fmaxf(vb, ob);
    }
  }
  const float twa = __shfl(va, 15, 64);
  const float twb = __shfl(vb, 15, 64);
  if (lane == 0) { wT[0][t >> 6] = twa; wT[1][t >> 6] = twb; }
  __syncthreads();
  const float Ta = fminf(fminf(wT[0][0], wT[0][1]), fminf(wT[0][2], wT[0][3]));
  const float Tb = fminf(fminf(wT[1][0], wT[1][1]), fminf(wT[1][2], wT[1][3]));
#pragma unroll
  for (int i = 0; i < 16; ++i) {
    if (da[i] <= Ta) {
      const u32 bits = __float_as_uint(da[i]);
      const u32 key = bits ^ ((u32)((int)bits >> 31) | 0x80000000u);
      const int pos = atomicAdd(&lcnt[0], 1);
      if (pos < 128) list[0][pos] = ((u64)key << 32) | (u32)(i * 256 + t);
    }
    if (db[i] <= Tb) {
      const u32 bits = __float_as_uint(db[i]);
      const u32 key = bits ^ ((u32)((int)bits >> 31) | 0x80000000u);
      const int pos = atomicAdd(&lcnt[1], 1);
      if (pos < 128) list[1][pos] = ((u64)key << 32) | (u32)(i * 256 + t);
    }
  }
  __syncthreads();
  if (t < 128) {
#pragma unroll
    for (int qq = 0; qq < 2; ++qq) {
      const int m = min(lcnt[qq], 128);
      const u64 my = (t < m) ? list[qq][t] : ~0ull;
      int rank = 0;
#pragma unroll 4
      for (int i = 0; i < m; ++i) rank += (list[qq][i] < my) ? 1 : 0;
      if (t < m && rank < 16)
        idx_out[(size_t)(g0 + qq) * KK + rank] = (int)(my & 0xFFFFFFFFull);
    }
  }
}

// ---------------- spider conv via f16 MFMA; A+B in LDS; tay computed INLINE ----------------
// Prologue computes the 48x64 f16 tay tile from xyzq+idx+w1 (bit-identical
// arithmetic to the old taylor kernel). Main loop identical to R12/R13.
// OTILE=64 (L1-L3): wave = 64o x 16p. OTILE=128 (L4): k-split, wave = 64o x 64p
// x half-K; ks-pairs merge partial sums via end-of-kernel LDS reduction.
template <int CPAD, int LOGC, int COUT, int OTILE>
__global__ __launch_bounds__(256) void conv_mfma_kernel(
    const char* __restrict__ ftin,        // f16 [NPTS][CPAD]
    const short* __restrict__ wb,         // f16 [OPAD][QTOT] permuted
    const float* __restrict__ b2,
    const float4* __restrict__ xyzq,      // f32 [NPTS] (x,y,z,|.|^2)
    const float* __restrict__ w1,         // f32 [3][20] (this layer)
    const float* __restrict__ b1,         // f32 [3]
    const int* __restrict__ idx,
    float* __restrict__ pfout, int pfbstride,
    short* __restrict__ ftout, int CPADN) {
  constexpr int QTOT = CPAD * 48;
  constexpr int OUTER = QTOT / 64;
  constexpr int NJ = OTILE / 64;          // 1: base path, 2: k-split path
  constexpr int NJC = (NJ == 2) ? 4 : 1;  // B frags per wave
  constexpr int NH = OTILE / 32;          // dma calls per A buffer
  __shared__ __align__(16) short As[2][OTILE * 64];
  __shared__ __align__(16) short Bs[2][64 * 64];
  __shared__ __align__(16) unsigned short tayH[48 * 64];
  __shared__ int idxS[16 * 64];
  const int t = threadIdx.x;
  const int pbase = blockIdx.x * 64;
  const int obase = blockIdx.y * OTILE;
  const int b = pbase >> 12;
  const int nbase = pbase & (NN - 1);
  const int p_loc = t >> 2;
  const int sub = t & 3;
  // ---- neighbor byte-offsets + INLINE tay tile (4 k's per thread) ----
  {
    const int4 mi = *(const int4*)&idx[(size_t)(pbase + p_loc) * KK + sub * 4];
    const int gb = b << 12;
    idxS[(sub * 4 + 0) * 64 + p_loc] = (gb + mi.x) << (LOGC + 1);
    idxS[(sub * 4 + 1) * 64 + p_loc] = (gb + mi.y) << (LOGC + 1);
    idxS[(sub * 4 + 2) * 64 + p_loc] = (gb + mi.z) << (LOGC + 1);
    idxS[(sub * 4 + 3) * 64 + p_loc] = (gb + mi.w) << (LOGC + 1);
    const float4 self = xyzq[pbase + p_loc];
    const int nbr[4] = {gb + mi.x, gb + mi.y, gb + mi.z, gb + mi.w};
#pragma unroll
    for (int j = 0; j < 4; ++j) {
      const float4 nb = xyzq[nbr[j]];
      const float x = nb.x - self.x;
      const float y = nb.y - self.y;
      const float z = nb.z - self.z;
      float tb[20];
      tb[0] = 1.0f; tb[1] = x; tb[2] = y; tb[3] = z;
      tb[4] = x * x; tb[5] = x * y; tb[6] = x * z;
      tb[7] = y * y; tb[8] = y * z; tb[9] = z * z;
      tb[10] = tb[4] * x; tb[11] = tb[4] * y; tb[12] = tb[4] * z;
      tb[13] = tb[5] * y; tb[14] = tb[5] * z; tb[15] = tb[6] * z;
      tb[16] = tb[7] * y; tb[17] = tb[7] * z; tb[18] = tb[8] * z; tb[19] = tb[9] * z;
      const int k = sub * 4 + j;
#pragma unroll
      for (int c = 0; c < 3; ++c) {
        float s = b1[c];
#pragma unroll
        for (int jj = 0; jj < 20; ++jj) s = fmaf(w1[c * 20 + jj], tb[jj], s);
        tayH[(c * 16 + k) * 64 + p_loc] = (unsigned short)f2h(s);
      }
    }
  }
  // ---- A dma lane setup (source permutation implements the XOR swizzle) ----
  const int arow = t >> 3;                 // 0..31
  const int apos = t & 7;                  // stored chunk position
  const int aswz = (t >> 4) & 7;           // (row>>1)&7
  const short* awl[NH];
#pragma unroll
  for (int h = 0; h < NH; ++h)
    awl[h] = wb + (size_t)(obase + h * 32 + arow) * QTOT + ((apos ^ aswz) * 8);
  auto dmaA = [&](int o, int ph) {
#pragma unroll
    for (int h = 0; h < NH; ++h)
      __builtin_amdgcn_global_load_lds(
          (const __attribute__((address_space(1))) u32*)(awl[h] + o * 64),
          (__attribute__((address_space(3))) u32*)&As[ph][h * 2048 + t * 8], 16, 0, 0);
  };
  // ---- wave mapping ----
  const int lane = t & 63;
  const int w = t >> 6;
  const int wm = (NJ == 2) ? (w & 1) : 0;   // o-half
  const int ksw = (NJ == 2) ? (w >> 1) : 0; // k-half (NJ==2 only)
  const int wn = (NJ == 2) ? 0 : w;         // p-sixteenth (NJ==1 only)
  const int fr = lane & 15;
  const int fk = lane >> 4;
  const int rsw = (fr >> 1) & 7;           // frag-read un-swizzle
  const int bswz = (p_loc >> 1) & 7;       // build-write swizzle
  f32x4 acc[4][NJC];
#pragma unroll
  for (int i = 0; i < 4; ++i)
#pragma unroll
    for (int j = 0; j < NJC; ++j) acc[i][j] = (f32x4)(0.0f);

  uint4 fv[2];
  unsigned short tvh[2];
  auto prefB = [&](int o) {
#pragma unroll
    for (int z = 0; z < 2; ++z) {
      const int q0 = o * 64 + z * 32 + sub * 8;
      const int kq = q0 >> LOGC;
      const int c0 = q0 & (CPAD - 1);
      const int moff = idxS[(kq & 15) * 64 + p_loc];
      tvh[z] = tayH[kq * 64 + p_loc];
      fv[z] = *(const uint4*)(ftin + moff + (c0 << 1));
    }
  };
  auto buildB = [&](int ph) {
#pragma unroll
    for (int z = 0; z < 2; ++z) {
      const __half2 t2 = __half2half2(__ushort_as_half(tvh[z]));
      const uint4 f = fv[z];
      uint4 r;
      r.x = mulh2(f.x, t2); r.y = mulh2(f.y, t2);
      r.z = mulh2(f.z, t2); r.w = mulh2(f.w, t2);
      const int pos = (z * 4 + sub) ^ bswz;
      *(uint4*)&Bs[ph][p_loc * 64 + pos * 8] = r;
    }
  };
  // ---- prologue ----
  dmaA(0, 0);
  __syncthreads();            // tayH/idxS visible; dma0 drained
  prefB(0);
  buildB(0);
  __syncthreads();            // Bs[0] visible
#pragma unroll 1
  for (int o = 0; o < OUTER; ++o) {
    const int ph = o & 1;
    if (o + 1 < OUTER) { dmaA(o + 1, ph ^ 1); prefB(o + 1); }
    if constexpr (NJ == 2) {
      f16x8 af[4], bf[4];
      const int pos8 = ((ksw * 4 + fk) ^ rsw) * 8;
#pragma unroll
      for (int i = 0; i < 4; ++i)
        af[i] = *(const f16x8*)&As[ph][(wm * 64 + i * 16 + fr) * 64 + pos8];
#pragma unroll
      for (int j = 0; j < 4; ++j)
        bf[j] = *(const f16x8*)&Bs[ph][(j * 16 + fr) * 64 + pos8];
      if (o + 1 < OUTER) buildB(ph ^ 1);
#pragma unroll
      for (int i = 0; i < 4; ++i)
#pragma unroll
        for (int j = 0; j < 4; ++j)
          acc[i][j] = __builtin_amdgcn_mfma_f32_16x16x32_f16(af[i], bf[j], acc[i][j], 0, 0, 0);
    } else {
#pragma unroll
      for (int z = 0; z < 2; ++z) {
        f16x8 af[4], bf;
        const int pos8 = ((z * 4 + fk) ^ rsw) * 8;
#pragma unroll
        for (int i = 0; i < 4; ++i)
          af[i] = *(const f16x8*)&As[ph][(i * 16 + fr) * 64 + pos8];
        bf = *(const f16x8*)&Bs[ph][(wn * 16 + fr) * 64 + pos8];
        if (z == 0 && o + 1 < OUTER) buildB(ph ^ 1);
#pragma unroll
        for (int i = 0; i < 4; ++i)
          acc[i][0] = __builtin_amdgcn_mfma_f32_16x16x32_f16(af[i], bf, acc[i][0], 0, 0, 0);
      }
    }
    if (o + 1 < OUTER) __syncthreads();
  }
  // ---- k-split reduction (NJ==2): merge ks-pair partial sums via As scratch ----
  if constexpr (NJ == 2) {
    __syncthreads();
    float* red = (float*)(&As[0][0]) + wm * 4096;
    if (ksw == 1) {
#pragma unroll
      for (int i = 0; i < 4; ++i)
#pragma unroll
        for (int j = 0; j < 4; ++j)
#pragma unroll
          for (int r = 0; r < 4; ++r)
            red[((i * 4 + j) * 4 + r) * 64 + lane] = acc[i][j][r];
    }
    __syncthreads();
    if (ksw == 1) return;
#pragma unroll
    for (int i = 0; i < 4; ++i)
#pragma unroll
      for (int j = 0; j < 4; ++j)
#pragma unroll
        for (int r = 0; r < 4; ++r)
          acc[i][j][r] += red[((i * 4 + j) * 4 + r) * 64 + lane];
  }
  // ---- epilogue: bias + relu; fp32 -> pf, f16 -> ft_next ----
  float* outb = pfout + (size_t)b * pfbstride;
#pragma unroll
  for (int i = 0; i < 4; ++i) {
    const int o0 = obase + wm * 64 + i * 16 + fk * 4;
    if (o0 < COUT) {
      const float4 b4 = *(const float4*)&b2[o0];
#pragma unroll
      for (int j = 0; j < NJC; ++j) {
        const int p_l = (NJ == 2) ? (j * 16 + fr) : (wn * 16 + fr);
        const float v0 = fmaxf(acc[i][j][0] + b4.x, 0.0f);
        const float v1 = fmaxf(acc[i][j][1] + b4.y, 0.0f);
        const float v2 = fmaxf(acc[i][j][2] + b4.z, 0.0f);
        const float v3 = fmaxf(acc[i][j][3] + b4.w, 0.0f);
        outb[(size_t)(o0 + 0) * NN + nbase + p_l] = v0;
        outb[(size_t)(o0 + 1) * NN + nbase + p_l] = v1;
        outb[(size_t)(o0 + 2) * NN + nbase + p_l] = v2;
        outb[(size_t)(o0 + 3) * NN + nbase + p_l] = v3;
        if (ftout) {
          const __half2 h01 = __floats2half2_rn(v0, v1);
          const __half2 h23 = __floats2half2_rn(v2, v3);
          uint2 pk;
          pk.x = *(const u32*)&h01;
          pk.y = *(const u32*)&h23;
          *(uint2*)&ftout[(size_t)(pbase + p_l) * CPADN + o0] = pk;
        }
      }
    }
  }
}

// ---------------- top-2 over N per (b, channel) ----------------
__global__ __launch_bounds__(256) void top2_kernel(const float* __restrict__ pf,
                                                   float* __restrict__ cat) {
  const int row = blockIdx.x;  // b*480 + ch
  const float* p = pf + (size_t)row * NN;
  float m1 = -FLT_MAX, m2 = -FLT_MAX;
  for (int i = threadIdx.x; i < NN; i += 256) {
    const float v = p[i];
    if (v > m1) { m2 = m1; m1 = v; }
    else if (v > m2) m2 = v;
  }
#pragma unroll
  for (int off = 32; off > 0; off >>= 1) {
    const float o1 = __shfl_down(m1, off, 64);
    const float o2 = __shfl_down(m2, off, 64);
    const float nm1 = fmaxf(m1, o1);
    const float nm2 = fmaxf(fminf(m1, o1), fmaxf(m2, o2));
    m1 = nm1; m2 = nm2;
  }
  __shared__ float s1[4], s2[4];
  const int wid = threadIdx.x >> 6;
  if ((threadIdx.x & 63) == 0) { s1[wid] = m1; s2[wid] = m2; }
  __syncthreads();
  if (threadIdx.x == 0) {
    m1 = s1[0]; m2 = s2[0];
#pragma unroll
    for (int w = 1; w < 4; ++w) {
      const float o1 = s1[w], o2 = s2[w];
      const float nm1 = fmaxf(m1, o1);
      const float nm2 = fmaxf(fminf(m1, o1), fmaxf(m2, o2));
      m1 = nm1; m2 = nm2;
    }
    const int b = row / 480, ch = row % 480;
    cat[b * 960 + ch * 2 + 0] = m1;
    cat[b * 960 + ch * 2 + 1] = m2;
  }
}

extern "C" void kernel_launch(void* const* d_in, const int* in_sizes, int n_in,
                              void* d_out, int out_size, void* d_ws, size_t ws_size,
                              hipStream_t stream) {
  const float* pc = (const float*)d_in[0];
  const float* w1s[4]; const float* b1s[4]; const float* w2s[4]; const float* b2s[4];
  for (int l = 0; l < 4; ++l) {
    w1s[l] = (const float*)d_in[1 + 4 * l];
    b1s[l] = (const float*)d_in[2 + 4 * l];
    w2s[l] = (const float*)d_in[3 + 4 * l];
    b2s[l] = (const float*)d_in[4 + 4 * l];
  }
  // ---- workspace layout (bytes), fully disjoint (no aliasing) ----
  char* W = (char*)d_ws;
  int* idx = (int*)W;                                  // 1,048,576
  float4* xyzq = (float4*)(W + 1048576);               // 262,144 (live: prep -> L4 conv)
  short* wb1 = (short*)(W + 1310720);                  //    49,152
  short* wb2 = (short*)(W + 1359872);                  //   196,608
  short* wb3 = (short*)(W + 1556480);                  //   786,432
  short* wb4 = (short*)(W + 2342912);                  // 3,145,728
  short* ft0 = (short*)(W + 5488640);                  //   262,144
  short* ft1 = (short*)(W + 5750784);                  // 1,048,576
  short* ft2 = (short*)(W + 6799360);                  // 2,097,152
  short* ft3 = (short*)(W + 8896512);                  // 4,194,304  (end 13,090,816)
  float* cat = (float*)d_out;                          // B*960
  float* pf = (float*)d_out + BB * 960;                // (B, 480, N)
  const int pfstride = 480 * NN;

  prep_kernel<<<dim3(1084), 256, 0, stream>>>(
      pc, ft0, xyzq, w2s[0], wb1, w2s[1], wb2, w2s[2], wb3, w2s[3], wb4);
  knn_select2<<<dim3(NPTS / 2), 256, 0, stream>>>(xyzq, idx);
  conv_mfma_kernel<8, 3, 32, 64><<<dim3(NPTS / 64, 1), 256, 0, stream>>>(
      (const char*)ft0, wb1, b2s[0], xyzq, w1s[0], b1s[0], idx,
      pf + (size_t)0 * NN, pfstride, ft1, 32);
  conv_mfma_kernel<32, 5, 64, 64><<<dim3(NPTS / 64, 1), 256, 0, stream>>>(
      (const char*)ft1, wb2, b2s[1], xyzq, w1s[1], b1s[1], idx,
      pf + (size_t)32 * NN, pfstride, ft2, 64);
  conv_mfma_kernel<64, 6, 128, 64><<<dim3(NPTS / 64, 2), 256, 0, stream>>>(
      (const char*)ft2, wb3, b2s[2], xyzq, w1s[2], b1s[2], idx,
      pf + (size_t)96 * NN, pfstride, ft3, 128);
  conv_mfma_kernel<128, 7, 256, 128><<<dim3(NPTS / 64, 2), 256, 0, stream>>>(
      (const char*)ft3, wb4, b2s[3], xyzq, w1s[3], b1s[3], idx,
      pf + (size_t)224 * NN, pfstride, nullptr, 0);
  top2_kernel<<<dim3(BB * 480), 256, 0, stream>>>(pf, cat);
}